// Round 12
// baseline (199.609 us; speedup 1.0000x reference)
//
#include <hip/hip_runtime.h>

#define TTOK   8192
#define BGR    32
#define NNODE  256
#define DIM    128
#define NH     8
#define HD     16
#define NEDGE  262144
#define SCALE_QK 0.25f

#define OWq   0
#define OWk   32768
#define OWv   65536
#define OWo   98304
#define OWg1  131072
#define OWg2  196608
#define OWm1  262144
#define OWm2  327680
#define OWamC 393216
#define OWamF 458752

typedef short bf16x8 __attribute__((ext_vector_type(8)));
typedef float f32x4  __attribute__((ext_vector_type(4)));

__device__ __forceinline__ ushort bf_hi(float x, float &rem) {
  unsigned u = __float_as_uint(x) & 0xffff0000u;
  rem = x - __uint_as_float(u);
  return (ushort)(u >> 16);
}
__device__ __forceinline__ ushort bf_rne(float x) {
  unsigned u = __float_as_uint(x);
  u += 0x7fffu + ((u >> 16) & 1u);
  return (ushort)(u >> 16);
}
__device__ __forceinline__ void cvt8(const float* av, bf16x8& ah, bf16x8& al) {
  #pragma unroll
  for (int i = 0; i < 8; i++) {
    float r;
    ah[i] = (short)bf_hi(av[i], r);
    al[i] = (short)bf_rne(r);
  }
}
__device__ __forceinline__ void mfma3(f32x4& acc, const bf16x8& ah, const bf16x8& al,
                                      const bf16x8& bh, const bf16x8& bl) {
  acc = __builtin_amdgcn_mfma_f32_16x16x32_bf16(ah, bh, acc, 0, 0, 0);
  acc = __builtin_amdgcn_mfma_f32_16x16x32_bf16(al, bh, acc, 0, 0, 0);
  acc = __builtin_amdgcn_mfma_f32_16x16x32_bf16(ah, bl, acc, 0, 0, 0);
}

// ---------------- Weight prep (+ dst histogram in extra y-slice) ----------------
struct WArg { const float* w[8]; int K[8]; int nlog[8]; int off[8]; };

__global__ __launch_bounds__(256) void wprep_k(WArg a, ushort* out,
                                               const int* __restrict__ ei,
                                               int* __restrict__ cnt) {
  if (blockIdx.y == 8) {
    const int e0 = blockIdx.x * 256 + threadIdx.x;
    for (int e = e0; e < NEDGE; e += 32768) atomicAdd(&cnt[ei[NEDGE + e]], 1);
    return;
  }
  const int m = blockIdx.y;
  const int K = a.K[m];
  const int nl = a.nlog[m];
  const int sz = K << nl;
  const int e = blockIdx.x * 256 + threadIdx.x;
  if (e >= sz) return;
  const int k = e >> nl, n = e & ((1 << nl) - 1);
  const float x = a.w[m][e];
  float r;
  const ushort h = bf_hi(x, r);
  const ushort l = bf_rne(r);
  const int idx = (((n >> 4) * (K >> 3) + (k >> 3)) << 7) + ((n & 15) << 3) + (k & 7);
  out[a.off[m] + idx] = h;
  out[a.off[m] + sz + idx] = l;
}

// ---------------- CSR scan (also zeroes entropy output slots) ----------------
__global__ __launch_bounds__(256) void scan_k(const int* __restrict__ cnt,
                                              int* __restrict__ off,
                                              int* __restrict__ cursor,
                                              float* __restrict__ entz)
{
  __shared__ int part[256];
  const int t = threadIdx.x;
  entz[t] = 0.f; entz[256 + t] = 0.f;
  const int base = t * 32;
  int local[32];
  int s = 0;
  #pragma unroll
  for (int i = 0; i < 32; i++) { local[i] = s; s += cnt[base + i]; }
  part[t] = s;
  __syncthreads();
  int pre = 0;
  for (int i = 0; i < t; i++) pre += part[i];
  #pragma unroll
  for (int i = 0; i < 32; i++) {
    const int v = pre + local[i];
    off[base + i] = v;
    cursor[base + i] = v;
  }
  if (t == 255) off[8192] = pre + s;
}

// ---------------- MFMA GEMM body (512 thr, 8 waves 2x4, wave-tile 32x32) ----------------
struct MJob {
  const float*  A1;
  const float*  A2;
  const ushort* Wh;
  const ushort* Wl;
  const float*  bias;
  const float*  res;
  float*        C;
};

template<int AMODE, int RELU, int HASRES, int K, int BNSUM>
__device__ __forceinline__ void gemm_body(const MJob jb, int by, int bx, int N,
                                          float* __restrict__ psum,
                                          float* __restrict__ psq, int t)
{
  __shared__ float sredS[128];
  __shared__ float sredQ[128];
  const int tid = threadIdx.x;
  const int w = tid >> 6, lane = tid & 63;
  const int wr = w >> 2, wc = w & 3;
  const int lr = lane & 15, lk = lane >> 4;
  const int bm = by * 64;
  const int bn = bx * 128;
  const int row0 = bm + wr * 32 + lr;
  constexpr int K8 = K / 8;
  f32x4 acc[2][2] = {};

  #pragma unroll
  for (int ks = 0; ks < K / 32; ks++) {
    bf16x8 ah[2], al[2];
    #pragma unroll
    for (int rt = 0; rt < 2; rt++) {
      const int row = row0 + rt * 16;
      float av[8];
      if (AMODE == 0) {
        const float* p = jb.A1 + (size_t)row * K + ks * 32 + lk * 8;
        const f32x4 u0 = *(const f32x4*)p;
        const f32x4 u1 = *(const f32x4*)(p + 4);
        av[0]=u0[0]; av[1]=u0[1]; av[2]=u0[2]; av[3]=u0[3];
        av[4]=u1[0]; av[5]=u1[1]; av[6]=u1[2]; av[7]=u1[3];
      } else if (AMODE == 1) {
        const float* p = jb.A1 + (size_t)row * 128 + ks * 32 + lk * 8;
        const float* q = jb.A2 + (size_t)row * 128 + ks * 32 + lk * 8;
        const f32x4 u0 = *(const f32x4*)p;
        const f32x4 u1 = *(const f32x4*)(p + 4);
        const f32x4 v0 = *(const f32x4*)q;
        const f32x4 v1 = *(const f32x4*)(q + 4);
        av[0]=u0[0]+v0[0]; av[1]=u0[1]+v0[1]; av[2]=u0[2]+v0[2]; av[3]=u0[3]+v0[3];
        av[4]=u1[0]+v1[0]; av[5]=u1[1]+v1[1]; av[6]=u1[2]+v1[2]; av[7]=u1[3]+v1[3];
      } else {
        const float* p = (ks * 32 < 128)
          ? jb.A1 + (size_t)row * 128 + ks * 32 + lk * 8
          : jb.A2 + (size_t)row * 128 + (ks * 32 - 128) + lk * 8;
        const f32x4 u0 = *(const f32x4*)p;
        const f32x4 u1 = *(const f32x4*)(p + 4);
        av[0]=u0[0]; av[1]=u0[1]; av[2]=u0[2]; av[3]=u0[3];
        av[4]=u1[0]; av[5]=u1[1]; av[6]=u1[2]; av[7]=u1[3];
      }
      cvt8(av, ah[rt], al[rt]);
    }
    #pragma unroll
    for (int ct = 0; ct < 2; ct++) {
      const int ntile = (bn >> 4) + wc * 2 + ct;
      const size_t foff = (((size_t)ntile * K8 + ks * 4 + lk) << 7) + ((size_t)lr << 3);
      const bf16x8 bh = *(const bf16x8*)(jb.Wh + foff);
      const bf16x8 bl = *(const bf16x8*)(jb.Wl + foff);
      mfma3(acc[0][ct], ah[0], al[0], bh, bl);
      mfma3(acc[1][ct], ah[1], al[1], bh, bl);
    }
  }

  float csv[2], cqv[2];
  #pragma unroll
  for (int ct = 0; ct < 2; ct++) {
    const int lcol = wc * 32 + ct * 16 + lr;
    const int col = bn + lcol;
    const float bb = jb.bias[col];
    float cs = 0.f, cq = 0.f;
    #pragma unroll
    for (int rt = 0; rt < 2; rt++) {
      #pragma unroll
      for (int r = 0; r < 4; r++) {
        const int row = bm + wr * 32 + rt * 16 + lk * 4 + r;
        float o = acc[rt][ct][r] + bb;
        if (RELU) o = fmaxf(o, 0.f);
        if (HASRES) o += jb.res[(size_t)row * N + col];
        jb.C[(size_t)row * N + col] = o;
        cs += o; cq = fmaf(o, o, cq);
      }
    }
    if (BNSUM) {
      cs += __shfl_xor(cs, 16); cq += __shfl_xor(cq, 16);
      cs += __shfl_xor(cs, 32); cq += __shfl_xor(cq, 32);
      csv[ct] = cs; cqv[ct] = cq;
      if (wr == 1 && lk == 0) { sredS[lcol] = cs; sredQ[lcol] = cq; }
    }
  }
  if (BNSUM) {
    __syncthreads();
    if (wr == 0 && lk == 0) {
      #pragma unroll
      for (int ct = 0; ct < 2; ct++) {
        const int lcol = wc * 32 + ct * 16 + lr;
        psum[((t << 7) + by) * 128 + lcol] = csv[ct] + sredS[lcol];
        psq [((t << 7) + by) * 128 + lcol] = cqv[ct] + sredQ[lcol];
      }
    }
  }
}

template<int AMODE, int RELU, int HASRES, int K, int BNSUM>
__global__ __launch_bounds__(512) void gemm_mfma_k(MJob j0, MJob j1, MJob j2, int N,
                                                   float* __restrict__ psum,
                                                   float* __restrict__ psq, int tix0)
{
  const MJob jb = (blockIdx.z == 0) ? j0 : ((blockIdx.z == 1) ? j1 : j2);
  gemm_body<AMODE,RELU,HASRES,K,BNSUM>(jb, blockIdx.y, blockIdx.x, N, psum, psq, tix0 + blockIdx.z);
}

// ---------------- Fused GINE layer1+layer2 (row-local chain, one kernel) ----------------
__global__ __launch_bounds__(512) void gine12_k(
    const float* __restrict__ x, const float* __restrict__ agc, const float* __restrict__ agf,
    const ushort* __restrict__ wfr,
    const float* __restrict__ bg1v, const float* __restrict__ bg2v,
    float* __restrict__ mcr, float* __restrict__ mfr,
    float* __restrict__ psum, float* __restrict__ psq)
{
  __shared__ float hs[64][260];
  __shared__ float sredS[128];
  __shared__ float sredQ[128];
  const int z = blockIdx.z;
  const float* A2 = z ? agf : agc;
  float* C = z ? mfr : mcr;
  const int tid = threadIdx.x;
  const int w = tid >> 6, lane = tid & 63;
  const int wr = w >> 2, wc = w & 3;
  const int lr = lane & 15, lk = lane >> 4;
  const int bm = blockIdx.y * 64;

  // Stage A: h = relu((x+ag) @ Wg1 + bg1), K=128, N=256 -> LDS
  {
    f32x4 acc[2][4] = {};
    const ushort* Wh = wfr + OWg1;
    const ushort* Wl = Wh + 32768;
    #pragma unroll
    for (int ks = 0; ks < 4; ks++) {
      bf16x8 ah[2], al[2];
      #pragma unroll
      for (int rt = 0; rt < 2; rt++) {
        const int row = bm + wr * 32 + rt * 16 + lr;
        const float* p = x  + (size_t)row * 128 + ks * 32 + lk * 8;
        const float* q = A2 + (size_t)row * 128 + ks * 32 + lk * 8;
        const f32x4 u0 = *(const f32x4*)p;
        const f32x4 u1 = *(const f32x4*)(p + 4);
        const f32x4 v0 = *(const f32x4*)q;
        const f32x4 v1 = *(const f32x4*)(q + 4);
        float av[8] = {u0[0]+v0[0], u0[1]+v0[1], u0[2]+v0[2], u0[3]+v0[3],
                       u1[0]+v1[0], u1[1]+v1[1], u1[2]+v1[2], u1[3]+v1[3]};
        cvt8(av, ah[rt], al[rt]);
      }
      #pragma unroll
      for (int ct = 0; ct < 4; ct++) {
        const int ntile = wc * 4 + ct;
        const size_t foff = (((size_t)ntile * 16 + ks * 4 + lk) << 7) + ((size_t)lr << 3);
        const bf16x8 bh = *(const bf16x8*)(Wh + foff);
        const bf16x8 bl = *(const bf16x8*)(Wl + foff);
        mfma3(acc[0][ct], ah[0], al[0], bh, bl);
        mfma3(acc[1][ct], ah[1], al[1], bh, bl);
      }
    }
    #pragma unroll
    for (int ct = 0; ct < 4; ct++) {
      const int col = wc * 64 + ct * 16 + lr;
      const float bb = bg1v[col];
      #pragma unroll
      for (int rt = 0; rt < 2; rt++) {
        #pragma unroll
        for (int r = 0; r < 4; r++) {
          const int lrow = wr * 32 + rt * 16 + lk * 4 + r;
          hs[lrow][col] = fmaxf(acc[rt][ct][r] + bb, 0.f);
        }
      }
    }
  }
  __syncthreads();
  // Stage B: m = h @ Wg2 + bg2, K=256, N=128, BNSUM t=2+z
  {
    f32x4 acc[2][2] = {};
    const ushort* Wh = wfr + OWg2;
    const ushort* Wl = Wh + 32768;
    #pragma unroll
    for (int ks = 0; ks < 8; ks++) {
      bf16x8 ah[2], al[2];
      #pragma unroll
      for (int rt = 0; rt < 2; rt++) {
        const int lrow = wr * 32 + rt * 16 + lr;
        const float* p = &hs[lrow][ks * 32 + lk * 8];
        const f32x4 u0 = *(const f32x4*)p;
        const f32x4 u1 = *(const f32x4*)(p + 4);
        float av[8] = {u0[0],u0[1],u0[2],u0[3],u1[0],u1[1],u1[2],u1[3]};
        cvt8(av, ah[rt], al[rt]);
      }
      #pragma unroll
      for (int ct = 0; ct < 2; ct++) {
        const int ntile = wc * 2 + ct;
        const size_t foff = (((size_t)ntile * 32 + ks * 4 + lk) << 7) + ((size_t)lr << 3);
        const bf16x8 bh = *(const bf16x8*)(Wh + foff);
        const bf16x8 bl = *(const bf16x8*)(Wl + foff);
        mfma3(acc[0][ct], ah[0], al[0], bh, bl);
        mfma3(acc[1][ct], ah[1], al[1], bh, bl);
      }
    }
    const int t = 2 + z;
    float csv[2], cqv[2];
    #pragma unroll
    for (int ct = 0; ct < 2; ct++) {
      const int lcol = wc * 32 + ct * 16 + lr;
      const float bb = bg2v[lcol];
      float cs = 0.f, cq = 0.f;
      #pragma unroll
      for (int rt = 0; rt < 2; rt++) {
        #pragma unroll
        for (int r = 0; r < 4; r++) {
          const int row = bm + wr * 32 + rt * 16 + lk * 4 + r;
          const float o = acc[rt][ct][r] + bb;
          C[(size_t)row * 128 + lcol] = o;
          cs += o; cq = fmaf(o, o, cq);
        }
      }
      cs += __shfl_xor(cs, 16); cq += __shfl_xor(cq, 16);
      cs += __shfl_xor(cs, 32); cq += __shfl_xor(cq, 32);
      csv[ct] = cs; cqv[ct] = cq;
      if (wr == 1 && lk == 0) { sredS[lcol] = cs; sredQ[lcol] = cq; }
    }
    __syncthreads();
    if (wr == 0 && lk == 0) {
      #pragma unroll
      for (int ct = 0; ct < 2; ct++) {
        const int lcol = wc * 32 + ct * 16 + lr;
        psum[((t << 7) + blockIdx.y) * 128 + lcol] = csv[ct] + sredS[lcol];
        psq [((t << 7) + blockIdx.y) * 128 + lcol] = cqv[ct] + sredQ[lcol];
      }
    }
  }
}

// ---------------- Fused fuse-linear + MLP1 + MLP2 (row-local chain) ----------------
__global__ __launch_bounds__(512) void fusemlp_k(
    const float* __restrict__ acr, const float* __restrict__ mcr,
    const float* __restrict__ afr, const float* __restrict__ mfr,
    const ushort* __restrict__ wfr,
    const float* __restrict__ biasC, const float* __restrict__ biasF,
    const float* __restrict__ bm1v, const float* __restrict__ bm2v,
    float* __restrict__ fmc, float* __restrict__ fmf,
    float* __restrict__ psum, float* __restrict__ psq)
{
  __shared__ float ft[64][132];
  __shared__ float hs[64][260];
  __shared__ float sredS[128];
  __shared__ float sredQ[128];
  const int z = blockIdx.z;
  const float* A1 = z ? afr : acr;
  const float* A2 = z ? mfr : mcr;
  const float* bA = z ? biasF : biasC;
  float* C = z ? fmf : fmc;
  const ushort* WamH = wfr + (z ? OWamF : OWamC);
  const int tid = threadIdx.x;
  const int w = tid >> 6, lane = tid & 63;
  const int wr = w >> 2, wc = w & 3;
  const int lr = lane & 15, lk = lane >> 4;
  const int bm = blockIdx.y * 64;

  // Stage A: f = concat(a, m) @ Wam' + bias', K=256, N=128 -> LDS ft
  {
    f32x4 acc[2][2] = {};
    const ushort* Wl = WamH + 32768;
    #pragma unroll
    for (int ks = 0; ks < 8; ks++) {
      bf16x8 ah[2], al[2];
      #pragma unroll
      for (int rt = 0; rt < 2; rt++) {
        const int row = bm + wr * 32 + rt * 16 + lr;
        const float* p = (ks < 4)
          ? A1 + (size_t)row * 128 + ks * 32 + lk * 8
          : A2 + (size_t)row * 128 + (ks - 4) * 32 + lk * 8;
        const f32x4 u0 = *(const f32x4*)p;
        const f32x4 u1 = *(const f32x4*)(p + 4);
        float av[8] = {u0[0],u0[1],u0[2],u0[3],u1[0],u1[1],u1[2],u1[3]};
        cvt8(av, ah[rt], al[rt]);
      }
      #pragma unroll
      for (int ct = 0; ct < 2; ct++) {
        const int ntile = wc * 2 + ct;
        const size_t foff = (((size_t)ntile * 32 + ks * 4 + lk) << 7) + ((size_t)lr << 3);
        const bf16x8 bh = *(const bf16x8*)(WamH + foff);
        const bf16x8 bl = *(const bf16x8*)(Wl + foff);
        mfma3(acc[0][ct], ah[0], al[0], bh, bl);
        mfma3(acc[1][ct], ah[1], al[1], bh, bl);
      }
    }
    #pragma unroll
    for (int ct = 0; ct < 2; ct++) {
      const int col = wc * 32 + ct * 16 + lr;
      const float bb = bA[col];
      #pragma unroll
      for (int rt = 0; rt < 2; rt++) {
        #pragma unroll
        for (int r = 0; r < 4; r++) {
          const int lrow = wr * 32 + rt * 16 + lk * 4 + r;
          ft[lrow][col] = acc[rt][ct][r] + bb;
        }
      }
    }
  }
  __syncthreads();
  // Stage B: h = relu(f @ Wm1 + bm1), K=128, N=256 -> LDS hs
  {
    f32x4 acc[2][4] = {};
    const ushort* Wh = wfr + OWm1;
    const ushort* Wl = Wh + 32768;
    #pragma unroll
    for (int ks = 0; ks < 4; ks++) {
      bf16x8 ah[2], al[2];
      #pragma unroll
      for (int rt = 0; rt < 2; rt++) {
        const int lrow = wr * 32 + rt * 16 + lr;
        const float* p = &ft[lrow][ks * 32 + lk * 8];
        const f32x4 u0 = *(const f32x4*)p;
        const f32x4 u1 = *(const f32x4*)(p + 4);
        float av[8] = {u0[0],u0[1],u0[2],u0[3],u1[0],u1[1],u1[2],u1[3]};
        cvt8(av, ah[rt], al[rt]);
      }
      #pragma unroll
      for (int ct = 0; ct < 4; ct++) {
        const int ntile = wc * 4 + ct;
        const size_t foff = (((size_t)ntile * 16 + ks * 4 + lk) << 7) + ((size_t)lr << 3);
        const bf16x8 bh = *(const bf16x8*)(Wh + foff);
        const bf16x8 bl = *(const bf16x8*)(Wl + foff);
        mfma3(acc[0][ct], ah[0], al[0], bh, bl);
        mfma3(acc[1][ct], ah[1], al[1], bh, bl);
      }
    }
    #pragma unroll
    for (int ct = 0; ct < 4; ct++) {
      const int col = wc * 64 + ct * 16 + lr;
      const float bb = bm1v[col];
      #pragma unroll
      for (int rt = 0; rt < 2; rt++) {
        #pragma unroll
        for (int r = 0; r < 4; r++) {
          const int lrow = wr * 32 + rt * 16 + lk * 4 + r;
          hs[lrow][col] = fmaxf(acc[rt][ct][r] + bb, 0.f);
        }
      }
    }
  }
  __syncthreads();
  // Stage C: out = h @ Wm2 + bm2 + f, K=256, N=128, BNSUM t=z
  {
    f32x4 acc[2][2] = {};
    const ushort* Wh = wfr + OWm2;
    const ushort* Wl = Wh + 32768;
    #pragma unroll
    for (int ks = 0; ks < 8; ks++) {
      bf16x8 ah[2], al[2];
      #pragma unroll
      for (int rt = 0; rt < 2; rt++) {
        const int lrow = wr * 32 + rt * 16 + lr;
        const float* p = &hs[lrow][ks * 32 + lk * 8];
        const f32x4 u0 = *(const f32x4*)p;
        const f32x4 u1 = *(const f32x4*)(p + 4);
        float av[8] = {u0[0],u0[1],u0[2],u0[3],u1[0],u1[1],u1[2],u1[3]};
        cvt8(av, ah[rt], al[rt]);
      }
      #pragma unroll
      for (int ct = 0; ct < 2; ct++) {
        const int ntile = wc * 2 + ct;
        const size_t foff = (((size_t)ntile * 32 + ks * 4 + lk) << 7) + ((size_t)lr << 3);
        const bf16x8 bh = *(const bf16x8*)(Wh + foff);
        const bf16x8 bl = *(const bf16x8*)(Wl + foff);
        mfma3(acc[0][ct], ah[0], al[0], bh, bl);
        mfma3(acc[1][ct], ah[1], al[1], bh, bl);
      }
    }
    float csv[2], cqv[2];
    #pragma unroll
    for (int ct = 0; ct < 2; ct++) {
      const int lcol = wc * 32 + ct * 16 + lr;
      const float bb = bm2v[lcol];
      float cs = 0.f, cq = 0.f;
      #pragma unroll
      for (int rt = 0; rt < 2; rt++) {
        #pragma unroll
        for (int r = 0; r < 4; r++) {
          const int lrow = wr * 32 + rt * 16 + lk * 4 + r;
          const float o = acc[rt][ct][r] + bb + ft[lrow][lcol];
          C[(size_t)(bm + lrow) * 128 + lcol] = o;
          cs += o; cq = fmaf(o, o, cq);
        }
      }
      cs += __shfl_xor(cs, 16); cq += __shfl_xor(cq, 16);
      cs += __shfl_xor(cs, 32); cq += __shfl_xor(cq, 32);
      csv[ct] = cs; cqv[ct] = cq;
      if (wr == 1 && lk == 0) { sredS[lcol] = cs; sredQ[lcol] = cq; }
    }
    __syncthreads();
    if (wr == 0 && lk == 0) {
      #pragma unroll
      for (int ct = 0; ct < 2; ct++) {
        const int lcol = wc * 32 + ct * 16 + lr;
        psum[((z << 7) + blockIdx.y) * 128 + lcol] = csv[ct] + sredS[lcol];
        psq [((z << 7) + blockIdx.y) * 128 + lcol] = cqv[ct] + sredQ[lcol];
      }
    }
  }
}

// ---------------- Fused gather + Wo GEMM (XCD-swizzled) ----------------
__global__ __launch_bounds__(512) void gather_wo_k(
    const float* __restrict__ x, const float* __restrict__ ea,
    const int* __restrict__ off, const int4* __restrict__ meta,
    float* __restrict__ aggrC, float* __restrict__ aggrF,
    MJob j0, MJob j1, float* __restrict__ psum, float* __restrict__ psq)
{
  const int xcd = blockIdx.x & 7;
  const int j = blockIdx.x >> 3;
  if (j < 32) {
    const int wid = xcd + 8 * j;
    gemm_body<0,0,0,128,1>((wid < 128) ? j0 : j1, wid & 127, 0, 128, psum, psq, wid >> 7);
    return;
  }
  const int jj = j - 32;
  const int g = xcd + 8 * (jj >> 8);
  const int n = g * 256 + (jj & 255);
  __shared__ float sC[16][128];
  __shared__ float sF[16][128];
  const int tid = threadIdx.x;
  const int s = tid >> 5;
  const int c4 = (tid & 31) * 4;
  const int end = off[n + 1];
  float4 aC = make_float4(0,0,0,0), aF = make_float4(0,0,0,0);
  for (int i = off[n] + s; i < end; i += 16) {
    const int4 md = meta[i];
    const float4 u = *(const float4*)(x  + (size_t)md.x * DIM + c4);
    const float4 w = *(const float4*)(ea + (size_t)md.y * DIM + c4);
    const float mc = __int_as_float(md.z);
    const float mf = 1.f - mc;
    const float g0 = fmaxf(u.x + w.x, 0.f);
    const float g1 = fmaxf(u.y + w.y, 0.f);
    const float g2 = fmaxf(u.z + w.z, 0.f);
    const float g3 = fmaxf(u.w + w.w, 0.f);
    aC.x = fmaf(g0, mc, aC.x); aC.y = fmaf(g1, mc, aC.y);
    aC.z = fmaf(g2, mc, aC.z); aC.w = fmaf(g3, mc, aC.w);
    aF.x = fmaf(g0, mf, aF.x); aF.y = fmaf(g1, mf, aF.y);
    aF.z = fmaf(g2, mf, aF.z); aF.w = fmaf(g3, mf, aF.w);
  }
  *(float4*)&sC[s][c4] = aC;
  *(float4*)&sF[s][c4] = aF;
  __syncthreads();
  if (tid < 128) {
    float t = 0.f;
    #pragma unroll
    for (int kk = 0; kk < 16; kk++) t += sC[kk][tid];
    aggrC[(size_t)n * DIM + tid] = t;
  } else if (tid < 256) {
    const int col = tid - 128;
    float t = 0.f;
    #pragma unroll
    for (int kk = 0; kk < 16; kk++) t += sF[kk][col];
    aggrF[(size_t)n * DIM + col] = t;
  }
}

// ---------------- Fused attention (256 blocks, 2 rows/pair, norm-bound shift)
//                  + edge mask/placement (8192 blocks), XCD-swizzled ----------------
__global__ __launch_bounds__(256) void attn_edge_k(
    const float* __restrict__ q, const float* __restrict__ k, const float* __restrict__ v,
    const float* __restrict__ tptr, float* __restrict__ fc, float* __restrict__ ff,
    const int* __restrict__ ei, float* __restrict__ maskout,
    int* __restrict__ cursor, int4* __restrict__ meta,
    float* __restrict__ dout)
{
  __shared__ float Ks[256][20];
  __shared__ float Vs[256][20];
  __shared__ float red[4][2];
  __shared__ float kmax_s[4];
  const int tid = threadIdx.x;
  const int xcd = blockIdx.x & 7;
  const int j = blockIdx.x >> 3;

  if (j >= 32) {
    const int jj = j - 32;
    const int g = xcd + 8 * (jj >> 8);
    const int s = jj & 255;
    const int e = g * 8192 + s * 32 + (tid >> 3);
    const int h = tid & 7;
    const int src = ei[e];
    const int dst = ei[NEDGE + e];
    const float* qr = q + (size_t)src * DIM + h*HD;
    const float* kr = k + (size_t)dst * DIM + h*HD;
    float sdot = 0.f;
    #pragma unroll
    for (int p = 0; p < 4; p++) {
      float4 a = *(const float4*)(qr + 4*p);
      float4 c = *(const float4*)(kr + 4*p);
      sdot += a.x*c.x + a.y*c.y + a.z*c.z + a.w*c.w;
    }
    sdot *= SCALE_QK;
    const float sig = 1.f / (1.f + __expf(-sdot));
    maskout[e * 8 + h] = sig;
    float m = sig;
    m += __shfl_xor(m, 1); m += __shfl_xor(m, 2); m += __shfl_xor(m, 4);
    if ((tid & 7) == 0) {
      const int pos = atomicAdd(&cursor[dst], 1);
      meta[pos] = make_int4(src, e, __float_as_int(m * 0.125f), 0);
    }
    return;
  }

  const int b = (j >> 3) * 8 + xcd;
  const int h = j & 7;
  const int bh = b * 8 + h;
  float k2 = 0.f;
  {
    const float* kr = k + ((size_t)(b*NNODE + tid))*DIM + h*HD;
    const float* vr = v + ((size_t)(b*NNODE + tid))*DIM + h*HD;
    #pragma unroll
    for (int p = 0; p < 4; p++) {
      float4 kv = *(const float4*)(kr + 4*p);
      *(float4*)&Ks[tid][4*p] = kv;
      k2 += kv.x*kv.x + kv.y*kv.y + kv.z*kv.z + kv.w*kv.w;
      *(float4*)&Vs[tid][4*p] = *(const float4*)(vr + 4*p);
    }
  }
  #pragma unroll
  for (int off = 1; off < 64; off <<= 1) k2 = fmaxf(k2, __shfl_xor(k2, off));
  if ((tid & 63) == 0) kmax_s[tid >> 6] = k2;
  const int pr  = tid >> 1;
  const int par = tid & 1;
  const int r0 = pr * 2;
  const float sc = SCALE_QK / tptr[0];
  float qa[16], qb[16];
  float q2a = 0.f, q2b = 0.f;
  {
    const float* qr = q + ((size_t)(b*NNODE + r0))*DIM + h*HD;
    #pragma unroll
    for (int p = 0; p < 4; p++) {
      float4 a = *(const float4*)(qr + 4*p);
      qa[4*p+0]=a.x*sc; qa[4*p+1]=a.y*sc; qa[4*p+2]=a.z*sc; qa[4*p+3]=a.w*sc;
      q2a += qa[4*p]*qa[4*p] + qa[4*p+1]*qa[4*p+1] + qa[4*p+2]*qa[4*p+2] + qa[4*p+3]*qa[4*p+3];
      float4 c = *(const float4*)(qr + DIM + 4*p);
      qb[4*p+0]=c.x*sc; qb[4*p+1]=c.y*sc; qb[4*p+2]=c.z*sc; qb[4*p+3]=c.w*sc;
      q2b += qb[4*p]*qb[4*p] + qb[4*p+1]*qb[4*p+1] + qb[4*p+2]*qb[4*p+2] + qb[4*p+3]*qb[4*p+3];
    }
  }
  __syncthreads();
  const float kmax2 = fmaxf(fmaxf(kmax_s[0], kmax_s[1]), fmaxf(kmax_s[2], kmax_s[3]));
  const float Ma = sqrtf(q2a * kmax2), Mb = sqrtf(q2b * kmax2);
  const float mna = -Ma, mnb = -Mb;

  float zca=0,zfa=0,Eca=0,Efa=0, zcb=0,zfb=0,Ecb=0,Efb=0;
  float oca[16], ofa[16], ocb[16], ofb[16];
  #pragma unroll
  for (int d = 0; d < 16; d++) { oca[d]=0.f; ofa[d]=0.f; ocb[d]=0.f; ofb[d]=0.f; }
  for (int jn = par; jn < NNODE; jn += 2) {
    const float4 k0 = *(const float4*)&Ks[jn][0];
    const float4 k1 = *(const float4*)&Ks[jn][4];
    const float4 k2v = *(const float4*)&Ks[jn][8];
    const float4 k3 = *(const float4*)&Ks[jn][12];
    float sa = qa[0]*k0.x; float sb = qb[0]*k0.x;
    sa = fmaf(qa[1],k0.y,sa); sb = fmaf(qb[1],k0.y,sb);
    sa = fmaf(qa[2],k0.z,sa); sb = fmaf(qb[2],k0.z,sb);
    sa = fmaf(qa[3],k0.w,sa); sb = fmaf(qb[3],k0.w,sb);
    sa = fmaf(qa[4],k1.x,sa); sb = fmaf(qb[4],k1.x,sb);
    sa = fmaf(qa[5],k1.y,sa); sb = fmaf(qb[5],k1.y,sb);
    sa = fmaf(qa[6],k1.z,sa); sb = fmaf(qb[6],k1.z,sb);
    sa = fmaf(qa[7],k1.w,sa); sb = fmaf(qb[7],k1.w,sb);
    sa = fmaf(qa[8],k2v.x,sa); sb = fmaf(qb[8],k2v.x,sb);
    sa = fmaf(qa[9],k2v.y,sa); sb = fmaf(qb[9],k2v.y,sb);
    sa = fmaf(qa[10],k2v.z,sa); sb = fmaf(qb[10],k2v.z,sb);
    sa = fmaf(qa[11],k2v.w,sa); sb = fmaf(qb[11],k2v.w,sb);
    sa = fmaf(qa[12],k3.x,sa); sb = fmaf(qb[12],k3.x,sb);
    sa = fmaf(qa[13],k3.y,sa); sb = fmaf(qb[13],k3.y,sb);
    sa = fmaf(qa[14],k3.z,sa); sb = fmaf(qb[14],k3.z,sb);
    sa = fmaf(qa[15],k3.w,sa); sb = fmaf(qb[15],k3.w,sb);
    const float eca = __expf(sa - Ma);
    const float efa = __expf(mna - sa);
    const float ecb = __expf(sb - Mb);
    const float efb = __expf(mnb - sb);
    zca += eca; zfa += efa; zcb += ecb; zfb += efb;
    Eca = fmaf(eca, sa, Eca); Efa = fmaf(efa, -sa, Efa);
    Ecb = fmaf(ecb, sb, Ecb); Efb = fmaf(efb, -sb, Efb);
    const float4 v0 = *(const float4*)&Vs[jn][0];
    const float4 v1 = *(const float4*)&Vs[jn][4];
    const float4 v2 = *(const float4*)&Vs[jn][8];
    const float4 v3 = *(const float4*)&Vs[jn][12];
    const float vv[16] = {v0.x,v0.y,v0.z,v0.w, v1.x,v1.y,v1.z,v1.w,
                          v2.x,v2.y,v2.z,v2.w, v3.x,v3.y,v3.z,v3.w};
    #pragma unroll
    for (int d = 0; d < 16; d++) {
      oca[d] = fmaf(eca, vv[d], oca[d]);
      ofa[d] = fmaf(efa, vv[d], ofa[d]);
      ocb[d] = fmaf(ecb, vv[d], ocb[d]);
      ofb[d] = fmaf(efb, vv[d], ofb[d]);
    }
  }
  zca += __shfl_xor(zca, 1); zfa += __shfl_xor(zfa, 1);
  zcb += __shfl_xor(zcb, 1); zfb += __shfl_xor(zfb, 1);
  Eca += __shfl_xor(Eca, 1); Efa += __shfl_xor(Efa, 1);
  Ecb += __shfl_xor(Ecb, 1); Efb += __shfl_xor(Efb, 1);
  #pragma unroll
  for (int d = 0; d < 16; d++) {
    oca[d] += __shfl_xor(oca[d], 1);
    ofa[d] += __shfl_xor(ofa[d], 1);
    ocb[d] += __shfl_xor(ocb[d], 1);
    ofb[d] += __shfl_xor(ofb[d], 1);
  }
  float entc = 0.f, entf = 0.f;
  if (par == 0) {
    const float rca = 1.f/zca, rfa = 1.f/zfa, rcb = 1.f/zcb, rfb = 1.f/zfb;
    entc = (Ma + __logf(zca) - Eca*rca) + (Mb + __logf(zcb) - Ecb*rcb);
    entf = (-mna + __logf(zfa) - Efa*rfa) + (-mnb + __logf(zfb) - Efb*rfb);
    float* pc = fc + ((size_t)(b*NNODE + r0))*DIM + h*HD;
    float* pf = ff + ((size_t)(b*NNODE + r0))*DIM + h*HD;
    #pragma unroll
    for (int p = 0; p < 4; p++) {
      *(float4*)(pc + 4*p)       = make_float4(oca[4*p]*rca, oca[4*p+1]*rca, oca[4*p+2]*rca, oca[4*p+3]*rca);
      *(float4*)(pc + DIM + 4*p) = make_float4(ocb[4*p]*rcb, ocb[4*p+1]*rcb, ocb[4*p+2]*rcb, ocb[4*p+3]*rcb);
      *(float4*)(pf + 4*p)       = make_float4(ofa[4*p]*rfa, ofa[4*p+1]*rfa, ofa[4*p+2]*rfa, ofa[4*p+3]*rfa);
      *(float4*)(pf + DIM + 4*p) = make_float4(ofb[4*p]*rfb, ofb[4*p+1]*rfb, ofb[4*p+2]*rfb, ofb[4*p+3]*rfb);
    }
  }
  #pragma unroll
  for (int off = 1; off < 64; off <<= 1) {
    entc += __shfl_xor(entc, off);
    entf += __shfl_xor(entf, off);
  }
  const int wv = tid >> 6;
  if ((tid & 63) == 0) { red[wv][0] = entc; red[wv][1] = entf; }
  __syncthreads();
  if (tid == 0) {
    const float tc = red[0][0]+red[1][0]+red[2][0]+red[3][0];
    const float tf = red[0][1]+red[1][1]+red[2][1]+red[3][1];
    dout[3145728 + bh] = tc * (1.0f/256.0f);
    dout[3145984 + bh] = tf * (1.0f/256.0f);
  }
}

// ---------------- Wam weights + bias, BN round-1 computed in-block ----------------
__global__ __launch_bounds__(256) void wamwb2_k(
    const float* __restrict__ Wam, const float* __restrict__ bam,
    const float* __restrict__ psum, const float* __restrict__ psq,
    const float* __restrict__ gA, const float* __restrict__ bA,
    const float* __restrict__ gM, const float* __restrict__ bM,
    ushort* __restrict__ outbase,
    float* __restrict__ biasC, float* __restrict__ biasF)
{
  __shared__ float2 ssl[4][128];   // attn-c, attn-f, mpnn-c, mpnn-f
  const int bx = blockIdx.x;
  const int tid = threadIdx.x;
  {
    const int col = tid & 127;
    for (int ti = tid >> 7; ti < 4; ti += 2) {
      float s = 0.f, sq = 0.f;
      #pragma unroll 8
      for (int c = 0; c < 128; c++) {
        s  += psum[((ti << 7) + c) * 128 + col];
        sq += psq [((ti << 7) + c) * 128 + col];
      }
      const float mean = s * (1.f/8192.f);
      const float var  = sq * (1.f/8192.f) - mean*mean;
      const float istd = rsqrtf(var + 1e-5f);
      const float g = (ti < 2) ? gA[col] : gM[col];
      const float bb = (ti < 2) ? bA[col] : bM[col];
      const float sc = g * istd;
      ssl[ti][col] = make_float2(sc, bb - mean*sc);
    }
  }
  __syncthreads();
  if (bx < 128) {
    const int e = bx * 256 + tid;
    const int k = e >> 7, n = e & 127;
    const float wv = Wam[e];
    const int idx = (((n >> 4) * 32 + (k >> 3)) << 7) + ((n & 15) << 3) + (k & 7);
    #pragma unroll
    for (int br = 0; br < 2; br++) {
      const float2 st = (k < 128) ? ssl[br][k] : ssl[2 + br][k - 128];
      const float wp = st.x * wv;
      float r;
      const ushort h = bf_hi(wp, r);
      const ushort l = bf_rne(r);
      ushort* oh = outbase + 393216 + br * 65536;
      oh[idx] = h; oh[32768 + idx] = l;
    }
    return;
  }
  __shared__ float lred[128];
  const int br = bx - 128;
  const int n = tid & 127, half = tid >> 7;
  const float2* st = half ? ssl[2 + br] : ssl[br];
  float a0=0.f, a1=0.f, a2=0.f, a3=0.f;
  #pragma unroll 8
  for (int kk = 0; kk < 128; kk += 4) {
    const int kb = half*128 + kk;
    a0 = fmaf(st[kk+0].y, Wam[(kb+0)*128 + n], a0);
    a1 = fmaf(st[kk+1].y, Wam[(kb+1)*128 + n], a1);
    a2 = fmaf(st[kk+2].y, Wam[(kb+2)*128 + n], a2);
    a3 = fmaf(st[kk+3].y, Wam[(kb+3)*128 + n], a3);
  }
  const float tot = (a0 + a1) + (a2 + a3);
  if (half) lred[n] = tot;
  __syncthreads();
  if (!half) {
    float* bout = br ? biasF : biasC;
    bout[n] = bam[n] + tot + lred[n];
  }
}

// ---------------- Final outputs, BN round-2 computed in-block + enc pass-through ----------------
__global__ __launch_bounds__(256) void final3_k(
    const float* __restrict__ fmc, const float* __restrict__ fmf,
    const float* __restrict__ psum, const float* __restrict__ psq,
    const float* __restrict__ g_mlp, const float* __restrict__ be_mlp,
    const float* __restrict__ cenc, const float* __restrict__ fenc,
    float* __restrict__ dout)
{
  const int bx = blockIdx.x;
  const int tid = threadIdx.x;
  if (bx >= 1024) {
    const int i = (bx - 1024) * 256 + tid;
    const float4 c = ((const float4*)cenc)[i];
    const float4 f = ((const float4*)fenc)[i];
    ((float4*)(dout + 3146240))[i] = c;
    ((float4*)(dout + 3277312))[i] = f;
    return;
  }
  __shared__ float2 sst[256];
  {
    const int ti = tid >> 7, col = tid & 127;
    float s = 0.f, sq = 0.f;
    #pragma unroll 8
    for (int c = 0; c < 128; c++) {
      s  += psum[((ti << 7) + c) * 128 + col];
      sq += psq [((ti << 7) + c) * 128 + col];
    }
    const float mean = s * (1.f/8192.f);
    const float var  = sq * (1.f/8192.f) - mean*mean;
    const float istd = rsqrtf(var + 1e-5f);
    const float sc = g_mlp[col] * istd;
    sst[tid] = make_float2(sc, be_mlp[col] - mean*sc);
  }
  __syncthreads();
  const int idx4 = bx * 256 + tid;
  const int base = idx4 * 4;
  const int col = base & 127;
  const float4 a = *(const float4*)(fmc + base);
  const float4 b = *(const float4*)(fmf + base);
  const float2 s0 = sst[col],     s1 = sst[col+1],     s2 = sst[col+2],     s3 = sst[col+3];
  const float2 t0 = sst[128+col], t1 = sst[128+col+1], t2 = sst[128+col+2], t3 = sst[128+col+3];
  const float c0 = a.x*s0.x + s0.y, c1 = a.y*s1.x + s1.y, c2 = a.z*s2.x + s2.y, c3 = a.w*s3.x + s3.y;
  const float f0 = b.x*t0.x + t0.y, f1 = b.y*t1.x + t1.y, f2 = b.z*t2.x + t2.y, f3 = b.w*t3.x + t3.y;
  *(float4*)(dout + 1048576 + base) = make_float4(c0,c1,c2,c3);
  *(float4*)(dout + 2097152 + base) = make_float4(f0,f1,f2,f3);
  *(float4*)(dout + base) = make_float4(0.5f*(c0+f0), 0.5f*(c1+f1), 0.5f*(c2+f2), 0.5f*(c3+f3));
}

// ---------------- Launcher ----------------
extern "C" void kernel_launch(void* const* d_in, const int* in_sizes, int n_in,
                              void* d_out, int out_size, void* d_ws, size_t ws_size,
                              hipStream_t stream)
{
  const float* x    = (const float*)d_in[0];
  const int*   ei   = (const int*)  d_in[2];
  const float* ea   = (const float*)d_in[3];
  const float* temp = (const float*)d_in[4];
  const float* cenc = (const float*)d_in[5];
  const float* fenc = (const float*)d_in[6];
  const float* Wq   = (const float*)d_in[7];
  const float* bq_v = (const float*)d_in[8];
  const float* Wk   = (const float*)d_in[9];
  const float* bk_v = (const float*)d_in[10];
  const float* Wv   = (const float*)d_in[11];
  const float* bv_v = (const float*)d_in[12];
  const float* Wo   = (const float*)d_in[13];
  const float* bo_v = (const float*)d_in[14];
  const float* Wg1  = (const float*)d_in[15];
  const float* bg1v = (const float*)d_in[16];
  const float* Wg2  = (const float*)d_in[17];
  const float* bg2v = (const float*)d_in[18];
  const float* Wam  = (const float*)d_in[19];
  const float* bamv = (const float*)d_in[20];
  const float* Wm1  = (const float*)d_in[21];
  const float* bm1v = (const float*)d_in[22];
  const float* Wm2  = (const float*)d_in[23];
  const float* bm2v = (const float*)d_in[24];
  const float* g_attn  = (const float*)d_in[25];
  const float* be_attn = (const float*)d_in[26];
  const float* g_mpnn  = (const float*)d_in[27];
  const float* be_mpnn = (const float*)d_in[28];
  const float* g_mlp   = (const float*)d_in[29];
  const float* be_mlp  = (const float*)d_in[30];

  float* out = (float*)d_out;
  float* ws  = (float*)d_ws;
  const size_t M1 = 1048576;

  float* q    = ws + 0*M1;
  float* kbuf = ws + 1*M1;
  float* vbuf = ws + 2*M1;
  float* fcp  = ws + 3*M1;
  float* ffp  = ws + 4*M1;
  float* acr  = ws + 5*M1;
  float* afr  = ws + 6*M1;
  float* agc  = ws + 7*M1;
  float* agf  = ws + 8*M1;
  float* psum = ws + 13*M1;            // 65536
  float* psq  = psum + 65536;          // 65536
  float* biasC = psq + 65536;          // 128
  float* biasF = biasC + 128;          // 128
  ushort* wfr = (ushort*)(ws + 14*M1); // 524288 ushorts (1MB)
  int4* meta  = (int4*)(ws + 16*M1);   // 4MB
  int* cnt    = (int*)(ws + 9*M1);
  int* off_a  = cnt + 8192;
  int* cursor = off_a + 8200;
  // reuses (sequenced by stream order)
  float* mcr = q;
  float* mfr = kbuf;
  float* fmc = ffp;
  float* fmf = agc;

  hipMemsetAsync(cnt, 0, 8192*sizeof(int), stream);

  const dim3 blk(256);
  const dim3 blk512(512);

  // Weight prep + dst histogram
  {
    WArg a;
    a.w[0]=Wq;  a.K[0]=128; a.nlog[0]=7; a.off[0]=OWq;
    a.w[1]=Wk;  a.K[1]=128; a.nlog[1]=7; a.off[1]=OWk;
    a.w[2]=Wv;  a.K[2]=128; a.nlog[2]=7; a.off[2]=OWv;
    a.w[3]=Wo;  a.K[3]=128; a.nlog[3]=7; a.off[3]=OWo;
    a.w[4]=Wg1; a.K[4]=128; a.nlog[4]=8; a.off[4]=OWg1;
    a.w[5]=Wg2; a.K[5]=256; a.nlog[5]=7; a.off[5]=OWg2;
    a.w[6]=Wm1; a.K[6]=128; a.nlog[6]=8; a.off[6]=OWm1;
    a.w[7]=Wm2; a.K[7]=256; a.nlog[7]=7; a.off[7]=OWm2;
    wprep_k<<<dim3(128, 9), blk, 0, stream>>>(a, wfr, ei, cnt);
  }
  // CSR scan + entropy-slot zeroing
  scan_k<<<dim3(1), blk, 0, stream>>>(cnt, off_a, cursor, out + 3145728);
  // QKV projections
  {
    MJob jq{x, nullptr, wfr+OWq, wfr+OWq+16384, bq_v, nullptr, q};
    MJob jk{x, nullptr, wfr+OWk, wfr+OWk+16384, bk_v, nullptr, kbuf};
    MJob jv{x, nullptr, wfr+OWv, wfr+OWv+16384, bv_v, nullptr, vbuf};
    gemm_mfma_k<0,0,0,128,0><<<dim3(1,128,3), blk512, 0, stream>>>(jq, jk, jv, 128, psum, psq, 0);
  }
  // Fused attention + entropy + edge masks + CSR placement (XCD-swizzled)
  attn_edge_k<<<dim3(8448), blk, 0, stream>>>(q, kbuf, vbuf, temp, fcp, ffp,
                                              ei, out + 3408384, cursor, meta, out);
  // Fused GINE gather + Wo projection (+ BN colsums t=0,1), XCD-swizzled
  {
    MJob j0{fcp, nullptr, wfr+OWo, wfr+OWo+16384, bo_v, nullptr, acr};
    MJob j1{ffp, nullptr, wfr+OWo, wfr+OWo+16384, bo_v, nullptr, afr};
    gather_wo_k<<<dim3(8448), blk512, 0, stream>>>(x, ea, off_a, meta, agc, agf,
                                                   j0, j1, psum, psq);
  }
  // Fused GINE layer1+layer2 (+ BN colsums t=2,3)
  gine12_k<<<dim3(1,128,2), blk512, 0, stream>>>(x, agc, agf, wfr, bg1v, bg2v,
                                                 mcr, mfr, psum, psq);
  // Fold BN round 1 into Wam weights + bias (BN computed in-block)
  wamwb2_k<<<dim3(130), blk, 0, stream>>>(Wam, bamv, psum, psq,
      g_attn, be_attn, g_mpnn, be_mpnn, wfr, biasC, biasF);
  // Fused fuse-linear + MLP1 + MLP2 (+ BN colsums t=0,1)
  fusemlp_k<<<dim3(1,128,2), blk512, 0, stream>>>(acr, mcr, afr, mfr, wfr,
                                                  biasC, biasF, bm1v, bm2v,
                                                  fmc, fmf, psum, psq);
  // Final features + new_x + encoding pass-through (BN round 2 in-block)
  final3_k<<<dim3(1152), blk, 0, stream>>>(fmc, fmf, psum, psq, g_mlp, be_mlp,
                                           cenc, fenc, out);
}

// Round 13
// 179.177 us; speedup vs baseline: 1.1140x; 1.1140x over previous
//
#include <hip/hip_runtime.h>

#define TTOK   8192
#define BGR    32
#define NNODE  256
#define DIM    128
#define NH     8
#define HD     16
#define NEDGE  262144
#define SCALE_QK 0.25f
#define BUCKET 96

#define OWq   0
#define OWk   32768
#define OWv   65536
#define OWo   98304
#define OWg1  131072
#define OWg2  196608
#define OWm1  262144
#define OWm2  327680
#define OWamC 393216
#define OWamF 458752

typedef short bf16x8 __attribute__((ext_vector_type(8)));
typedef float f32x4  __attribute__((ext_vector_type(4)));

__device__ __forceinline__ ushort bf_hi(float x, float &rem) {
  unsigned u = __float_as_uint(x) & 0xffff0000u;
  rem = x - __uint_as_float(u);
  return (ushort)(u >> 16);
}
__device__ __forceinline__ ushort bf_rne(float x) {
  unsigned u = __float_as_uint(x);
  u += 0x7fffu + ((u >> 16) & 1u);
  return (ushort)(u >> 16);
}
__device__ __forceinline__ void cvt8(const float* av, bf16x8& ah, bf16x8& al) {
  #pragma unroll
  for (int i = 0; i < 8; i++) {
    float r;
    ah[i] = (short)bf_hi(av[i], r);
    al[i] = (short)bf_rne(r);
  }
}
__device__ __forceinline__ void mfma3(f32x4& acc, const bf16x8& ah, const bf16x8& al,
                                      const bf16x8& bh, const bf16x8& bl) {
  acc = __builtin_amdgcn_mfma_f32_16x16x32_bf16(ah, bh, acc, 0, 0, 0);
  acc = __builtin_amdgcn_mfma_f32_16x16x32_bf16(al, bh, acc, 0, 0, 0);
  acc = __builtin_amdgcn_mfma_f32_16x16x32_bf16(ah, bl, acc, 0, 0, 0);
}

// ---------------- Weight prep ----------------
struct WArg { const float* w[8]; int K[8]; int nlog[8]; int off[8]; };

__global__ __launch_bounds__(256) void wprep_k(WArg a, ushort* out) {
  const int m = blockIdx.y;
  const int K = a.K[m];
  const int nl = a.nlog[m];
  const int sz = K << nl;
  const int e = blockIdx.x * 256 + threadIdx.x;
  if (e >= sz) return;
  const int k = e >> nl, n = e & ((1 << nl) - 1);
  const float x = a.w[m][e];
  float r;
  const ushort h = bf_hi(x, r);
  const ushort l = bf_rne(r);
  const int idx = (((n >> 4) * (K >> 3) + (k >> 3)) << 7) + ((n & 15) << 3) + (k & 7);
  out[a.off[m] + idx] = h;
  out[a.off[m] + sz + idx] = l;
}

// ---------------- MFMA GEMM body (512 thr, 8 waves 2x4, wave-tile 32x32) ----------------
struct MJob {
  const float*  A1;
  const float*  A2;
  const ushort* Wh;
  const ushort* Wl;
  const float*  bias;
  const float*  res;
  float*        C;
};

template<int AMODE, int RELU, int HASRES, int K, int BNSUM>
__device__ __forceinline__ void gemm_body(const MJob jb, int by, int bx, int N,
                                          float* __restrict__ psum,
                                          float* __restrict__ psq, int t)
{
  __shared__ float sredS[128];
  __shared__ float sredQ[128];
  const int tid = threadIdx.x;
  const int w = tid >> 6, lane = tid & 63;
  const int wr = w >> 2, wc = w & 3;
  const int lr = lane & 15, lk = lane >> 4;
  const int bm = by * 64;
  const int bn = bx * 128;
  const int row0 = bm + wr * 32 + lr;
  constexpr int K8 = K / 8;
  f32x4 acc[2][2] = {};

  #pragma unroll
  for (int ks = 0; ks < K / 32; ks++) {
    bf16x8 ah[2], al[2];
    #pragma unroll
    for (int rt = 0; rt < 2; rt++) {
      const int row = row0 + rt * 16;
      float av[8];
      if (AMODE == 0) {
        const float* p = jb.A1 + (size_t)row * K + ks * 32 + lk * 8;
        const f32x4 u0 = *(const f32x4*)p;
        const f32x4 u1 = *(const f32x4*)(p + 4);
        av[0]=u0[0]; av[1]=u0[1]; av[2]=u0[2]; av[3]=u0[3];
        av[4]=u1[0]; av[5]=u1[1]; av[6]=u1[2]; av[7]=u1[3];
      } else if (AMODE == 1) {
        const float* p = jb.A1 + (size_t)row * 128 + ks * 32 + lk * 8;
        const float* q = jb.A2 + (size_t)row * 128 + ks * 32 + lk * 8;
        const f32x4 u0 = *(const f32x4*)p;
        const f32x4 u1 = *(const f32x4*)(p + 4);
        const f32x4 v0 = *(const f32x4*)q;
        const f32x4 v1 = *(const f32x4*)(q + 4);
        av[0]=u0[0]+v0[0]; av[1]=u0[1]+v0[1]; av[2]=u0[2]+v0[2]; av[3]=u0[3]+v0[3];
        av[4]=u1[0]+v1[0]; av[5]=u1[1]+v1[1]; av[6]=u1[2]+v1[2]; av[7]=u1[3]+v1[3];
      } else {
        const float* p = (ks * 32 < 128)
          ? jb.A1 + (size_t)row * 128 + ks * 32 + lk * 8
          : jb.A2 + (size_t)row * 128 + (ks * 32 - 128) + lk * 8;
        const f32x4 u0 = *(const f32x4*)p;
        const f32x4 u1 = *(const f32x4*)(p + 4);
        av[0]=u0[0]; av[1]=u0[1]; av[2]=u0[2]; av[3]=u0[3];
        av[4]=u1[0]; av[5]=u1[1]; av[6]=u1[2]; av[7]=u1[3];
      }
      cvt8(av, ah[rt], al[rt]);
    }
    #pragma unroll
    for (int ct = 0; ct < 2; ct++) {
      const int ntile = (bn >> 4) + wc * 2 + ct;
      const size_t foff = (((size_t)ntile * K8 + ks * 4 + lk) << 7) + ((size_t)lr << 3);
      const bf16x8 bh = *(const bf16x8*)(jb.Wh + foff);
      const bf16x8 bl = *(const bf16x8*)(jb.Wl + foff);
      mfma3(acc[0][ct], ah[0], al[0], bh, bl);
      mfma3(acc[1][ct], ah[1], al[1], bh, bl);
    }
  }

  float csv[2], cqv[2];
  #pragma unroll
  for (int ct = 0; ct < 2; ct++) {
    const int lcol = wc * 32 + ct * 16 + lr;
    const int col = bn + lcol;
    const float bb = jb.bias[col];
    float cs = 0.f, cq = 0.f;
    #pragma unroll
    for (int rt = 0; rt < 2; rt++) {
      #pragma unroll
      for (int r = 0; r < 4; r++) {
        const int row = bm + wr * 32 + rt * 16 + lk * 4 + r;
        float o = acc[rt][ct][r] + bb;
        if (RELU) o = fmaxf(o, 0.f);
        if (HASRES) o += jb.res[(size_t)row * N + col];
        jb.C[(size_t)row * N + col] = o;
        cs += o; cq = fmaf(o, o, cq);
      }
    }
    if (BNSUM) {
      cs += __shfl_xor(cs, 16); cq += __shfl_xor(cq, 16);
      cs += __shfl_xor(cs, 32); cq += __shfl_xor(cq, 32);
      csv[ct] = cs; cqv[ct] = cq;
      if (wr == 1 && lk == 0) { sredS[lcol] = cs; sredQ[lcol] = cq; }
    }
  }
  if (BNSUM) {
    __syncthreads();
    if (wr == 0 && lk == 0) {
      #pragma unroll
      for (int ct = 0; ct < 2; ct++) {
        const int lcol = wc * 32 + ct * 16 + lr;
        psum[((t << 7) + by) * 128 + lcol] = csv[ct] + sredS[lcol];
        psq [((t << 7) + by) * 128 + lcol] = cqv[ct] + sredQ[lcol];
      }
    }
  }
}

template<int AMODE, int RELU, int HASRES, int K, int BNSUM>
__global__ __launch_bounds__(512) void gemm_mfma_k(MJob j0, MJob j1, MJob j2, int N,
                                                   float* __restrict__ psum,
                                                   float* __restrict__ psq, int tix0)
{
  const MJob jb = (blockIdx.z == 0) ? j0 : ((blockIdx.z == 1) ? j1 : j2);
  gemm_body<AMODE,RELU,HASRES,K,BNSUM>(jb, blockIdx.y, blockIdx.x, N, psum, psq, tix0 + blockIdx.z);
}

// ---------------- Fused GINE layer1+layer2 ----------------
__global__ __launch_bounds__(512) void gine12_k(
    const float* __restrict__ x, const float* __restrict__ agc, const float* __restrict__ agf,
    const ushort* __restrict__ wfr,
    const float* __restrict__ bg1v, const float* __restrict__ bg2v,
    float* __restrict__ mcr, float* __restrict__ mfr,
    float* __restrict__ psum, float* __restrict__ psq)
{
  __shared__ float hs[64][260];
  __shared__ float sredS[128];
  __shared__ float sredQ[128];
  const int z = blockIdx.z;
  const float* A2 = z ? agf : agc;
  float* C = z ? mfr : mcr;
  const int tid = threadIdx.x;
  const int w = tid >> 6, lane = tid & 63;
  const int wr = w >> 2, wc = w & 3;
  const int lr = lane & 15, lk = lane >> 4;
  const int bm = blockIdx.y * 64;

  {
    f32x4 acc[2][4] = {};
    const ushort* Wh = wfr + OWg1;
    const ushort* Wl = Wh + 32768;
    #pragma unroll
    for (int ks = 0; ks < 4; ks++) {
      bf16x8 ah[2], al[2];
      #pragma unroll
      for (int rt = 0; rt < 2; rt++) {
        const int row = bm + wr * 32 + rt * 16 + lr;
        const float* p = x  + (size_t)row * 128 + ks * 32 + lk * 8;
        const float* q = A2 + (size_t)row * 128 + ks * 32 + lk * 8;
        const f32x4 u0 = *(const f32x4*)p;
        const f32x4 u1 = *(const f32x4*)(p + 4);
        const f32x4 v0 = *(const f32x4*)q;
        const f32x4 v1 = *(const f32x4*)(q + 4);
        float av[8] = {u0[0]+v0[0], u0[1]+v0[1], u0[2]+v0[2], u0[3]+v0[3],
                       u1[0]+v1[0], u1[1]+v1[1], u1[2]+v1[2], u1[3]+v1[3]};
        cvt8(av, ah[rt], al[rt]);
      }
      #pragma unroll
      for (int ct = 0; ct < 4; ct++) {
        const int ntile = wc * 4 + ct;
        const size_t foff = (((size_t)ntile * 16 + ks * 4 + lk) << 7) + ((size_t)lr << 3);
        const bf16x8 bh = *(const bf16x8*)(Wh + foff);
        const bf16x8 bl = *(const bf16x8*)(Wl + foff);
        mfma3(acc[0][ct], ah[0], al[0], bh, bl);
        mfma3(acc[1][ct], ah[1], al[1], bh, bl);
      }
    }
    #pragma unroll
    for (int ct = 0; ct < 4; ct++) {
      const int col = wc * 64 + ct * 16 + lr;
      const float bb = bg1v[col];
      #pragma unroll
      for (int rt = 0; rt < 2; rt++) {
        #pragma unroll
        for (int r = 0; r < 4; r++) {
          const int lrow = wr * 32 + rt * 16 + lk * 4 + r;
          hs[lrow][col] = fmaxf(acc[rt][ct][r] + bb, 0.f);
        }
      }
    }
  }
  __syncthreads();
  {
    f32x4 acc[2][2] = {};
    const ushort* Wh = wfr + OWg2;
    const ushort* Wl = Wh + 32768;
    #pragma unroll
    for (int ks = 0; ks < 8; ks++) {
      bf16x8 ah[2], al[2];
      #pragma unroll
      for (int rt = 0; rt < 2; rt++) {
        const int lrow = wr * 32 + rt * 16 + lr;
        const float* p = &hs[lrow][ks * 32 + lk * 8];
        const f32x4 u0 = *(const f32x4*)p;
        const f32x4 u1 = *(const f32x4*)(p + 4);
        float av[8] = {u0[0],u0[1],u0[2],u0[3],u1[0],u1[1],u1[2],u1[3]};
        cvt8(av, ah[rt], al[rt]);
      }
      #pragma unroll
      for (int ct = 0; ct < 2; ct++) {
        const int ntile = wc * 2 + ct;
        const size_t foff = (((size_t)ntile * 32 + ks * 4 + lk) << 7) + ((size_t)lr << 3);
        const bf16x8 bh = *(const bf16x8*)(Wh + foff);
        const bf16x8 bl = *(const bf16x8*)(Wl + foff);
        mfma3(acc[0][ct], ah[0], al[0], bh, bl);
        mfma3(acc[1][ct], ah[1], al[1], bh, bl);
      }
    }
    const int t = 2 + z;
    float csv[2], cqv[2];
    #pragma unroll
    for (int ct = 0; ct < 2; ct++) {
      const int lcol = wc * 32 + ct * 16 + lr;
      const float bb = bg2v[lcol];
      float cs = 0.f, cq = 0.f;
      #pragma unroll
      for (int rt = 0; rt < 2; rt++) {
        #pragma unroll
        for (int r = 0; r < 4; r++) {
          const int row = bm + wr * 32 + rt * 16 + lk * 4 + r;
          const float o = acc[rt][ct][r] + bb;
          C[(size_t)row * 128 + lcol] = o;
          cs += o; cq = fmaf(o, o, cq);
        }
      }
      cs += __shfl_xor(cs, 16); cq += __shfl_xor(cq, 16);
      cs += __shfl_xor(cs, 32); cq += __shfl_xor(cq, 32);
      csv[ct] = cs; cqv[ct] = cq;
      if (wr == 1 && lk == 0) { sredS[lcol] = cs; sredQ[lcol] = cq; }
    }
    __syncthreads();
    if (wr == 0 && lk == 0) {
      #pragma unroll
      for (int ct = 0; ct < 2; ct++) {
        const int lcol = wc * 32 + ct * 16 + lr;
        psum[((t << 7) + blockIdx.y) * 128 + lcol] = csv[ct] + sredS[lcol];
        psq [((t << 7) + blockIdx.y) * 128 + lcol] = cqv[ct] + sredQ[lcol];
      }
    }
  }
}

// ---------------- Fused fuse-linear + MLP1 + MLP2 ----------------
__global__ __launch_bounds__(512) void fusemlp_k(
    const float* __restrict__ acr, const float* __restrict__ mcr,
    const float* __restrict__ afr, const float* __restrict__ mfr,
    const ushort* __restrict__ wfr,
    const float* __restrict__ biasC, const float* __restrict__ biasF,
    const float* __restrict__ bm1v, const float* __restrict__ bm2v,
    float* __restrict__ fmc, float* __restrict__ fmf,
    float* __restrict__ psum, float* __restrict__ psq)
{
  __shared__ float ft[64][132];
  __shared__ float hs[64][260];
  __shared__ float sredS[128];
  __shared__ float sredQ[128];
  const int z = blockIdx.z;
  const float* A1 = z ? afr : acr;
  const float* A2 = z ? mfr : mcr;
  const float* bA = z ? biasF : biasC;
  float* C = z ? fmf : fmc;
  const ushort* WamH = wfr + (z ? OWamF : OWamC);
  const int tid = threadIdx.x;
  const int w = tid >> 6, lane = tid & 63;
  const int wr = w >> 2, wc = w & 3;
  const int lr = lane & 15, lk = lane >> 4;
  const int bm = blockIdx.y * 64;

  {
    f32x4 acc[2][2] = {};
    const ushort* Wl = WamH + 32768;
    #pragma unroll
    for (int ks = 0; ks < 8; ks++) {
      bf16x8 ah[2], al[2];
      #pragma unroll
      for (int rt = 0; rt < 2; rt++) {
        const int row = bm + wr * 32 + rt * 16 + lr;
        const float* p = (ks < 4)
          ? A1 + (size_t)row * 128 + ks * 32 + lk * 8
          : A2 + (size_t)row * 128 + (ks - 4) * 32 + lk * 8;
        const f32x4 u0 = *(const f32x4*)p;
        const f32x4 u1 = *(const f32x4*)(p + 4);
        float av[8] = {u0[0],u0[1],u0[2],u0[3],u1[0],u1[1],u1[2],u1[3]};
        cvt8(av, ah[rt], al[rt]);
      }
      #pragma unroll
      for (int ct = 0; ct < 2; ct++) {
        const int ntile = wc * 2 + ct;
        const size_t foff = (((size_t)ntile * 32 + ks * 4 + lk) << 7) + ((size_t)lr << 3);
        const bf16x8 bh = *(const bf16x8*)(WamH + foff);
        const bf16x8 bl = *(const bf16x8*)(Wl + foff);
        mfma3(acc[0][ct], ah[0], al[0], bh, bl);
        mfma3(acc[1][ct], ah[1], al[1], bh, bl);
      }
    }
    #pragma unroll
    for (int ct = 0; ct < 2; ct++) {
      const int col = wc * 32 + ct * 16 + lr;
      const float bb = bA[col];
      #pragma unroll
      for (int rt = 0; rt < 2; rt++) {
        #pragma unroll
        for (int r = 0; r < 4; r++) {
          const int lrow = wr * 32 + rt * 16 + lk * 4 + r;
          ft[lrow][col] = acc[rt][ct][r] + bb;
        }
      }
    }
  }
  __syncthreads();
  {
    f32x4 acc[2][4] = {};
    const ushort* Wh = wfr + OWm1;
    const ushort* Wl = Wh + 32768;
    #pragma unroll
    for (int ks = 0; ks < 4; ks++) {
      bf16x8 ah[2], al[2];
      #pragma unroll
      for (int rt = 0; rt < 2; rt++) {
        const int lrow = wr * 32 + rt * 16 + lr;
        const float* p = &ft[lrow][ks * 32 + lk * 8];
        const f32x4 u0 = *(const f32x4*)p;
        const f32x4 u1 = *(const f32x4*)(p + 4);
        float av[8] = {u0[0],u0[1],u0[2],u0[3],u1[0],u1[1],u1[2],u1[3]};
        cvt8(av, ah[rt], al[rt]);
      }
      #pragma unroll
      for (int ct = 0; ct < 4; ct++) {
        const int ntile = wc * 4 + ct;
        const size_t foff = (((size_t)ntile * 16 + ks * 4 + lk) << 7) + ((size_t)lr << 3);
        const bf16x8 bh = *(const bf16x8*)(Wh + foff);
        const bf16x8 bl = *(const bf16x8*)(Wl + foff);
        mfma3(acc[0][ct], ah[0], al[0], bh, bl);
        mfma3(acc[1][ct], ah[1], al[1], bh, bl);
      }
    }
    #pragma unroll
    for (int ct = 0; ct < 4; ct++) {
      const int col = wc * 64 + ct * 16 + lr;
      const float bb = bm1v[col];
      #pragma unroll
      for (int rt = 0; rt < 2; rt++) {
        #pragma unroll
        for (int r = 0; r < 4; r++) {
          const int lrow = wr * 32 + rt * 16 + lk * 4 + r;
          hs[lrow][col] = fmaxf(acc[rt][ct][r] + bb, 0.f);
        }
      }
    }
  }
  __syncthreads();
  {
    f32x4 acc[2][2] = {};
    const ushort* Wh = wfr + OWm2;
    const ushort* Wl = Wh + 32768;
    #pragma unroll
    for (int ks = 0; ks < 8; ks++) {
      bf16x8 ah[2], al[2];
      #pragma unroll
      for (int rt = 0; rt < 2; rt++) {
        const int lrow = wr * 32 + rt * 16 + lr;
        const float* p = &hs[lrow][ks * 32 + lk * 8];
        const f32x4 u0 = *(const f32x4*)p;
        const f32x4 u1 = *(const f32x4*)(p + 4);
        float av[8] = {u0[0],u0[1],u0[2],u0[3],u1[0],u1[1],u1[2],u1[3]};
        cvt8(av, ah[rt], al[rt]);
      }
      #pragma unroll
      for (int ct = 0; ct < 2; ct++) {
        const int ntile = wc * 2 + ct;
        const size_t foff = (((size_t)ntile * 32 + ks * 4 + lk) << 7) + ((size_t)lr << 3);
        const bf16x8 bh = *(const bf16x8*)(Wh + foff);
        const bf16x8 bl = *(const bf16x8*)(Wl + foff);
        mfma3(acc[0][ct], ah[0], al[0], bh, bl);
        mfma3(acc[1][ct], ah[1], al[1], bh, bl);
      }
    }
    float csv[2], cqv[2];
    #pragma unroll
    for (int ct = 0; ct < 2; ct++) {
      const int lcol = wc * 32 + ct * 16 + lr;
      const float bb = bm2v[lcol];
      float cs = 0.f, cq = 0.f;
      #pragma unroll
      for (int rt = 0; rt < 2; rt++) {
        #pragma unroll
        for (int r = 0; r < 4; r++) {
          const int lrow = wr * 32 + rt * 16 + lk * 4 + r;
          const float o = acc[rt][ct][r] + bb + ft[lrow][lcol];
          C[(size_t)(bm + lrow) * 128 + lcol] = o;
          cs += o; cq = fmaf(o, o, cq);
        }
      }
      cs += __shfl_xor(cs, 16); cq += __shfl_xor(cq, 16);
      cs += __shfl_xor(cs, 32); cq += __shfl_xor(cq, 32);
      csv[ct] = cs; cqv[ct] = cq;
      if (wr == 1 && lk == 0) { sredS[lcol] = cs; sredQ[lcol] = cq; }
    }
    __syncthreads();
    if (wr == 0 && lk == 0) {
      #pragma unroll
      for (int ct = 0; ct < 2; ct++) {
        const int lcol = wc * 32 + ct * 16 + lr;
        psum[((z << 7) + blockIdx.y) * 128 + lcol] = csv[ct] + sredS[lcol];
        psq [((z << 7) + blockIdx.y) * 128 + lcol] = cqv[ct] + sredQ[lcol];
      }
    }
  }
}

// ---------------- Fused gather + Wo GEMM (XCD-swizzled, fixed buckets) ----------------
__global__ __launch_bounds__(512) void gather_wo_k(
    const float* __restrict__ x, const float* __restrict__ ea,
    const int* __restrict__ cnt, const int4* __restrict__ meta,
    float* __restrict__ aggrC, float* __restrict__ aggrF,
    MJob j0, MJob j1, float* __restrict__ psum, float* __restrict__ psq)
{
  const int xcd = blockIdx.x & 7;
  const int j = blockIdx.x >> 3;
  if (j < 32) {
    const int wid = xcd + 8 * j;
    gemm_body<0,0,0,128,1>((wid < 128) ? j0 : j1, wid & 127, 0, 128, psum, psq, wid >> 7);
    return;
  }
  const int jj = j - 32;
  const int g = xcd + 8 * (jj >> 8);
  const int n = g * 256 + (jj & 255);
  __shared__ float sC[16][128];
  __shared__ float sF[16][128];
  const int tid = threadIdx.x;
  const int s = tid >> 5;
  const int c4 = (tid & 31) * 4;
  const int base = n * BUCKET;
  const int end = base + cnt[n];
  float4 aC = make_float4(0,0,0,0), aF = make_float4(0,0,0,0);
  for (int i = base + s; i < end; i += 16) {
    const int4 md = meta[i];
    const float4 u = *(const float4*)(x  + (size_t)md.x * DIM + c4);
    const float4 w = *(const float4*)(ea + (size_t)md.y * DIM + c4);
    const float mc = __int_as_float(md.z);
    const float mf = 1.f - mc;
    const float g0 = fmaxf(u.x + w.x, 0.f);
    const float g1 = fmaxf(u.y + w.y, 0.f);
    const float g2 = fmaxf(u.z + w.z, 0.f);
    const float g3 = fmaxf(u.w + w.w, 0.f);
    aC.x = fmaf(g0, mc, aC.x); aC.y = fmaf(g1, mc, aC.y);
    aC.z = fmaf(g2, mc, aC.z); aC.w = fmaf(g3, mc, aC.w);
    aF.x = fmaf(g0, mf, aF.x); aF.y = fmaf(g1, mf, aF.y);
    aF.z = fmaf(g2, mf, aF.z); aF.w = fmaf(g3, mf, aF.w);
  }
  *(float4*)&sC[s][c4] = aC;
  *(float4*)&sF[s][c4] = aF;
  __syncthreads();
  if (tid < 128) {
    float t = 0.f;
    #pragma unroll
    for (int kk = 0; kk < 16; kk++) t += sC[kk][tid];
    aggrC[(size_t)n * DIM + tid] = t;
  } else if (tid < 256) {
    const int col = tid - 128;
    float t = 0.f;
    #pragma unroll
    for (int kk = 0; kk < 16; kk++) t += sF[kk][col];
    aggrF[(size_t)n * DIM + col] = t;
  }
}

// ---------------- Fused attention (256 blocks, 2 rows/pair, norm-bound shift)
//                  + edge mask/bucket placement (8192 blocks), XCD-swizzled ----------------
__global__ __launch_bounds__(256) void attn_edge_k(
    const float* __restrict__ q, const float* __restrict__ k, const float* __restrict__ v,
    const float* __restrict__ tptr, float* __restrict__ fc, float* __restrict__ ff,
    const int* __restrict__ ei, float* __restrict__ maskout,
    int* __restrict__ cursor, int4* __restrict__ meta,
    float* __restrict__ dout)
{
  __shared__ float Ks[256][20];
  __shared__ float Vs[256][20];
  __shared__ float red[4][2];
  __shared__ float kmax_s[4];
  const int tid = threadIdx.x;
  const int xcd = blockIdx.x & 7;
  const int j = blockIdx.x >> 3;

  if (j >= 32) {
    const int jj = j - 32;
    const int g = xcd + 8 * (jj >> 8);
    const int s = jj & 255;
    const int e = g * 8192 + s * 32 + (tid >> 3);
    const int h = tid & 7;
    const int src = ei[e];
    const int dst = ei[NEDGE + e];
    const float* qr = q + (size_t)src * DIM + h*HD;
    const float* kr = k + (size_t)dst * DIM + h*HD;
    float sdot = 0.f;
    #pragma unroll
    for (int p = 0; p < 4; p++) {
      float4 a = *(const float4*)(qr + 4*p);
      float4 c = *(const float4*)(kr + 4*p);
      sdot += a.x*c.x + a.y*c.y + a.z*c.z + a.w*c.w;
    }
    sdot *= SCALE_QK;
    const float sig = 1.f / (1.f + __expf(-sdot));
    maskout[e * 8 + h] = sig;
    float m = sig;
    m += __shfl_xor(m, 1); m += __shfl_xor(m, 2); m += __shfl_xor(m, 4);
    if ((tid & 7) == 0) {
      const int pos = atomicAdd(&cursor[dst], 1);
      meta[dst * BUCKET + pos] = make_int4(src, e, __float_as_int(m * 0.125f), 0);
    }
    return;
  }

  const int b = (j >> 3) * 8 + xcd;
  const int h = j & 7;
  const int bh = b * 8 + h;
  float k2 = 0.f;
  {
    const float* kr = k + ((size_t)(b*NNODE + tid))*DIM + h*HD;
    const float* vr = v + ((size_t)(b*NNODE + tid))*DIM + h*HD;
    #pragma unroll
    for (int p = 0; p < 4; p++) {
      float4 kv = *(const float4*)(kr + 4*p);
      *(float4*)&Ks[tid][4*p] = kv;
      k2 += kv.x*kv.x + kv.y*kv.y + kv.z*kv.z + kv.w*kv.w;
      *(float4*)&Vs[tid][4*p] = *(const float4*)(vr + 4*p);
    }
  }
  #pragma unroll
  for (int off = 1; off < 64; off <<= 1) k2 = fmaxf(k2, __shfl_xor(k2, off));
  if ((tid & 63) == 0) kmax_s[tid >> 6] = k2;
  const int pr  = tid >> 1;
  const int par = tid & 1;
  const int r0 = pr * 2;
  const float sc = SCALE_QK / tptr[0];
  float qa[16], qb[16];
  float q2a = 0.f, q2b = 0.f;
  {
    const float* qr = q + ((size_t)(b*NNODE + r0))*DIM + h*HD;
    #pragma unroll
    for (int p = 0; p < 4; p++) {
      float4 a = *(const float4*)(qr + 4*p);
      qa[4*p+0]=a.x*sc; qa[4*p+1]=a.y*sc; qa[4*p+2]=a.z*sc; qa[4*p+3]=a.w*sc;
      q2a += qa[4*p]*qa[4*p] + qa[4*p+1]*qa[4*p+1] + qa[4*p+2]*qa[4*p+2] + qa[4*p+3]*qa[4*p+3];
      float4 c = *(const float4*)(qr + DIM + 4*p);
      qb[4*p+0]=c.x*sc; qb[4*p+1]=c.y*sc; qb[4*p+2]=c.z*sc; qb[4*p+3]=c.w*sc;
      q2b += qb[4*p]*qb[4*p] + qb[4*p+1]*qb[4*p+1] + qb[4*p+2]*qb[4*p+2] + qb[4*p+3]*qb[4*p+3];
    }
  }
  __syncthreads();
  const float kmax2 = fmaxf(fmaxf(kmax_s[0], kmax_s[1]), fmaxf(kmax_s[2], kmax_s[3]));
  const float Ma = sqrtf(q2a * kmax2), Mb = sqrtf(q2b * kmax2);
  const float mna = -Ma, mnb = -Mb;

  float zca=0,zfa=0,Eca=0,Efa=0, zcb=0,zfb=0,Ecb=0,Efb=0;
  float oca[16], ofa[16], ocb[16], ofb[16];
  #pragma unroll
  for (int d = 0; d < 16; d++) { oca[d]=0.f; ofa[d]=0.f; ocb[d]=0.f; ofb[d]=0.f; }
  for (int jn = par; jn < NNODE; jn += 2) {
    const float4 k0 = *(const float4*)&Ks[jn][0];
    const float4 k1 = *(const float4*)&Ks[jn][4];
    const float4 k2v = *(const float4*)&Ks[jn][8];
    const float4 k3 = *(const float4*)&Ks[jn][12];
    float sa = qa[0]*k0.x; float sb = qb[0]*k0.x;
    sa = fmaf(qa[1],k0.y,sa); sb = fmaf(qb[1],k0.y,sb);
    sa = fmaf(qa[2],k0.z,sa); sb = fmaf(qb[2],k0.z,sb);
    sa = fmaf(qa[3],k0.w,sa); sb = fmaf(qb[3],k0.w,sb);
    sa = fmaf(qa[4],k1.x,sa); sb = fmaf(qb[4],k1.x,sb);
    sa = fmaf(qa[5],k1.y,sa); sb = fmaf(qb[5],k1.y,sb);
    sa = fmaf(qa[6],k1.z,sa); sb = fmaf(qb[6],k1.z,sb);
    sa = fmaf(qa[7],k1.w,sa); sb = fmaf(qb[7],k1.w,sb);
    sa = fmaf(qa[8],k2v.x,sa); sb = fmaf(qb[8],k2v.x,sb);
    sa = fmaf(qa[9],k2v.y,sa); sb = fmaf(qb[9],k2v.y,sb);
    sa = fmaf(qa[10],k2v.z,sa); sb = fmaf(qb[10],k2v.z,sb);
    sa = fmaf(qa[11],k2v.w,sa); sb = fmaf(qb[11],k2v.w,sb);
    sa = fmaf(qa[12],k3.x,sa); sb = fmaf(qb[12],k3.x,sb);
    sa = fmaf(qa[13],k3.y,sa); sb = fmaf(qb[13],k3.y,sb);
    sa = fmaf(qa[14],k3.z,sa); sb = fmaf(qb[14],k3.z,sb);
    sa = fmaf(qa[15],k3.w,sa); sb = fmaf(qb[15],k3.w,sb);
    const float eca = __expf(sa - Ma);
    const float efa = __expf(mna - sa);
    const float ecb = __expf(sb - Mb);
    const float efb = __expf(mnb - sb);
    zca += eca; zfa += efa; zcb += ecb; zfb += efb;
    Eca = fmaf(eca, sa, Eca); Efa = fmaf(efa, -sa, Efa);
    Ecb = fmaf(ecb, sb, Ecb); Efb = fmaf(efb, -sb, Efb);
    const float4 v0 = *(const float4*)&Vs[jn][0];
    const float4 v1 = *(const float4*)&Vs[jn][4];
    const float4 v2 = *(const float4*)&Vs[jn][8];
    const float4 v3 = *(const float4*)&Vs[jn][12];
    const float vv[16] = {v0.x,v0.y,v0.z,v0.w, v1.x,v1.y,v1.z,v1.w,
                          v2.x,v2.y,v2.z,v2.w, v3.x,v3.y,v3.z,v3.w};
    #pragma unroll
    for (int d = 0; d < 16; d++) {
      oca[d] = fmaf(eca, vv[d], oca[d]);
      ofa[d] = fmaf(efa, vv[d], ofa[d]);
      ocb[d] = fmaf(ecb, vv[d], ocb[d]);
      ofb[d] = fmaf(efb, vv[d], ofb[d]);
    }
  }
  zca += __shfl_xor(zca, 1); zfa += __shfl_xor(zfa, 1);
  zcb += __shfl_xor(zcb, 1); zfb += __shfl_xor(zfb, 1);
  Eca += __shfl_xor(Eca, 1); Efa += __shfl_xor(Efa, 1);
  Ecb += __shfl_xor(Ecb, 1); Efb += __shfl_xor(Efb, 1);
  #pragma unroll
  for (int d = 0; d < 16; d++) {
    oca[d] += __shfl_xor(oca[d], 1);
    ofa[d] += __shfl_xor(ofa[d], 1);
    ocb[d] += __shfl_xor(ocb[d], 1);
    ofb[d] += __shfl_xor(ofb[d], 1);
  }
  float entc = 0.f, entf = 0.f;
  if (par == 0) {
    const float rca = 1.f/zca, rfa = 1.f/zfa, rcb = 1.f/zcb, rfb = 1.f/zfb;
    entc = (Ma + __logf(zca) - Eca*rca) + (Mb + __logf(zcb) - Ecb*rcb);
    entf = (-mna + __logf(zfa) - Efa*rfa) + (-mnb + __logf(zfb) - Efb*rfb);
    float* pc = fc + ((size_t)(b*NNODE + r0))*DIM + h*HD;
    float* pf = ff + ((size_t)(b*NNODE + r0))*DIM + h*HD;
    #pragma unroll
    for (int p = 0; p < 4; p++) {
      *(float4*)(pc + 4*p)       = make_float4(oca[4*p]*rca, oca[4*p+1]*rca, oca[4*p+2]*rca, oca[4*p+3]*rca);
      *(float4*)(pc + DIM + 4*p) = make_float4(ocb[4*p]*rcb, ocb[4*p+1]*rcb, ocb[4*p+2]*rcb, ocb[4*p+3]*rcb);
      *(float4*)(pf + 4*p)       = make_float4(ofa[4*p]*rfa, ofa[4*p+1]*rfa, ofa[4*p+2]*rfa, ofa[4*p+3]*rfa);
      *(float4*)(pf + DIM + 4*p) = make_float4(ofb[4*p]*rfb, ofb[4*p+1]*rfb, ofb[4*p+2]*rfb, ofb[4*p+3]*rfb);
    }
  }
  #pragma unroll
  for (int off = 1; off < 64; off <<= 1) {
    entc += __shfl_xor(entc, off);
    entf += __shfl_xor(entf, off);
  }
  const int wv = tid >> 6;
  if ((tid & 63) == 0) { red[wv][0] = entc; red[wv][1] = entf; }
  __syncthreads();
  if (tid == 0) {
    const float tc = red[0][0]+red[1][0]+red[2][0]+red[3][0];
    const float tf = red[0][1]+red[1][1]+red[2][1]+red[3][1];
    dout[3145728 + bh] = tc * (1.0f/256.0f);
    dout[3145984 + bh] = tf * (1.0f/256.0f);
  }
}

// ---------------- BN scale/shift from psum/psq (parallel, unrolled) ----------------
__global__ __launch_bounds__(256) void bnss_k(
    const float* __restrict__ psum, const float* __restrict__ psq,
    const float* g0, const float* g1, const float* g2, const float* g3,
    const float* b0, const float* b1, const float* b2, const float* b3,
    float2* __restrict__ out)
{
  __shared__ float ls[128], lq[128];
  const int ti = blockIdx.x;
  const int tid = threadIdx.x;
  const int col = tid & 127, half = tid >> 7;
  const float* g = (ti == 0) ? g0 : (ti == 1) ? g1 : (ti == 2) ? g2 : g3;
  const float* bb = (ti == 0) ? b0 : (ti == 1) ? b1 : (ti == 2) ? b2 : b3;
  float s = 0.f, sq = 0.f;
  const int cbase = half * 64;
  #pragma unroll 8
  for (int c = 0; c < 64; c++) {
    s  += psum[(ti*128 + cbase + c)*128 + col];
    sq += psq [(ti*128 + cbase + c)*128 + col];
  }
  if (half) { ls[col] = s; lq[col] = sq; }
  __syncthreads();
  if (!half) {
    s += ls[col]; sq += lq[col];
    const float mean = s * (1.f/8192.f);
    const float var  = sq * (1.f/8192.f) - mean*mean;
    const float istd = rsqrtf(var + 1e-5f);
    const float sc = g[col] * istd;
    out[ti*128 + col] = make_float2(sc, bb[col] - mean*sc);
  }
}

// ---------------- Wam weights + bias (merged) ----------------
__global__ __launch_bounds__(256) void wamwb_k(const float* __restrict__ Wam,
                                               const float* __restrict__ bam,
                                               const float2* __restrict__ ss,
                                               ushort* __restrict__ outbase,
                                               float* __restrict__ biasC,
                                               float* __restrict__ biasF)
{
  const int bx = blockIdx.x;
  const int tid = threadIdx.x;
  if (bx < 128) {
    const int e = bx * 256 + tid;
    const int k = e >> 7, n = e & 127;
    const float wv = Wam[e];
    const int idx = (((n >> 4) * 32 + (k >> 3)) << 7) + ((n & 15) << 3) + (k & 7);
    #pragma unroll
    for (int br = 0; br < 2; br++) {
      const float2 st = (k < 128) ? ss[br*128 + k] : ss[(2+br)*128 + (k-128)];
      const float wp = st.x * wv;
      float r;
      const ushort h = bf_hi(wp, r);
      const ushort l = bf_rne(r);
      ushort* oh = outbase + 393216 + br * 65536;
      oh[idx] = h; oh[32768 + idx] = l;
    }
    return;
  }
  __shared__ float l[128];
  const int br = bx - 128;
  const int n = tid & 127, half = tid >> 7;
  const float2* st = ss + (half ? (2+br)*128 : br*128);
  float a0=0.f, a1=0.f, a2=0.f, a3=0.f;
  #pragma unroll 8
  for (int kk = 0; kk < 128; kk += 4) {
    const int kb = half*128 + kk;
    a0 = fmaf(st[kk+0].y, Wam[(kb+0)*128 + n], a0);
    a1 = fmaf(st[kk+1].y, Wam[(kb+1)*128 + n], a1);
    a2 = fmaf(st[kk+2].y, Wam[(kb+2)*128 + n], a2);
    a3 = fmaf(st[kk+3].y, Wam[(kb+3)*128 + n], a3);
  }
  const float tot = (a0 + a1) + (a2 + a3);
  if (half) l[n] = tot;
  __syncthreads();
  if (!half) {
    float* bout = br ? biasF : biasC;
    bout[n] = bam[n] + tot + l[n];
  }
}

// ---------------- Final outputs + encoding pass-through ----------------
__global__ __launch_bounds__(256) void final2_k(
    const float* __restrict__ fmc, const float* __restrict__ fmf,
    const float2* __restrict__ sst2,
    const float* __restrict__ cenc, const float* __restrict__ fenc,
    float* __restrict__ dout)
{
  const int bx = blockIdx.x;
  const int tid = threadIdx.x;
  if (bx >= 1024) {
    const int i = (bx - 1024) * 256 + tid;
    const float4 c = ((const float4*)cenc)[i];
    const float4 f = ((const float4*)fenc)[i];
    ((float4*)(dout + 3146240))[i] = c;
    ((float4*)(dout + 3277312))[i] = f;
    return;
  }
  const int idx4 = bx * 256 + tid;
  const int base = idx4 * 4;
  const int col = base & 127;
  const float4 a = *(const float4*)(fmc + base);
  const float4 b = *(const float4*)(fmf + base);
  const float2 s0 = sst2[col],     s1 = sst2[col+1],     s2 = sst2[col+2],     s3 = sst2[col+3];
  const float2 t0 = sst2[128+col], t1 = sst2[128+col+1], t2 = sst2[128+col+2], t3 = sst2[128+col+3];
  const float c0 = a.x*s0.x + s0.y, c1 = a.y*s1.x + s1.y, c2 = a.z*s2.x + s2.y, c3 = a.w*s3.x + s3.y;
  const float f0 = b.x*t0.x + t0.y, f1 = b.y*t1.x + t1.y, f2 = b.z*t2.x + t2.y, f3 = b.w*t3.x + t3.y;
  *(float4*)(dout + 1048576 + base) = make_float4(c0,c1,c2,c3);
  *(float4*)(dout + 2097152 + base) = make_float4(f0,f1,f2,f3);
  *(float4*)(dout + base) = make_float4(0.5f*(c0+f0), 0.5f*(c1+f1), 0.5f*(c2+f2), 0.5f*(c3+f3));
}

// ---------------- Launcher ----------------
extern "C" void kernel_launch(void* const* d_in, const int* in_sizes, int n_in,
                              void* d_out, int out_size, void* d_ws, size_t ws_size,
                              hipStream_t stream)
{
  const float* x    = (const float*)d_in[0];
  const int*   ei   = (const int*)  d_in[2];
  const float* ea   = (const float*)d_in[3];
  const float* temp = (const float*)d_in[4];
  const float* cenc = (const float*)d_in[5];
  const float* fenc = (const float*)d_in[6];
  const float* Wq   = (const float*)d_in[7];
  const float* bq_v = (const float*)d_in[8];
  const float* Wk   = (const float*)d_in[9];
  const float* bk_v = (const float*)d_in[10];
  const float* Wv   = (const float*)d_in[11];
  const float* bv_v = (const float*)d_in[12];
  const float* Wo   = (const float*)d_in[13];
  const float* bo_v = (const float*)d_in[14];
  const float* Wg1  = (const float*)d_in[15];
  const float* bg1v = (const float*)d_in[16];
  const float* Wg2  = (const float*)d_in[17];
  const float* bg2v = (const float*)d_in[18];
  const float* Wam  = (const float*)d_in[19];
  const float* bamv = (const float*)d_in[20];
  const float* Wm1  = (const float*)d_in[21];
  const float* bm1v = (const float*)d_in[22];
  const float* Wm2  = (const float*)d_in[23];
  const float* bm2v = (const float*)d_in[24];
  const float* g_attn  = (const float*)d_in[25];
  const float* be_attn = (const float*)d_in[26];
  const float* g_mpnn  = (const float*)d_in[27];
  const float* be_mpnn = (const float*)d_in[28];
  const float* g_mlp   = (const float*)d_in[29];
  const float* be_mlp  = (const float*)d_in[30];

  float* out = (float*)d_out;
  float* ws  = (float*)d_ws;
  const size_t M1 = 1048576;

  float* q    = ws + 0*M1;
  float* kbuf = ws + 1*M1;
  float* vbuf = ws + 2*M1;
  float* fcp  = ws + 3*M1;
  float* ffp  = ws + 4*M1;
  float* acr  = ws + 5*M1;
  float* afr  = ws + 6*M1;
  float* agc  = ws + 7*M1;
  float* agf  = ws + 8*M1;
  float* psum = ws + 13*M1;            // 65536
  float* psq  = psum + 65536;          // 65536
  float* biasC = psq + 65536;          // 128
  float* biasF = biasC + 128;          // 128
  float2* ssr1 = (float2*)(biasF + 128); // 512 float2
  float2* sst2 = ssr1 + 512;             // 256 float2
  ushort* wfr = (ushort*)(ws + 14*M1); // 1MB
  int4* meta  = (int4*)(ws + 16*M1);   // 8192*96*16B = 12.6MB
  int* cursor = (int*)(ws + 9*M1);     // 8192 (doubles as per-node count)
  // reuses (sequenced by stream order)
  float* mcr = q;
  float* mfr = kbuf;
  float* fmc = ffp;
  float* fmf = agc;

  hipMemsetAsync(cursor, 0, 8192*sizeof(int), stream);

  const dim3 blk(256);
  const dim3 blk512(512);

  // Weight prep
  {
    WArg a;
    a.w[0]=Wq;  a.K[0]=128; a.nlog[0]=7; a.off[0]=OWq;
    a.w[1]=Wk;  a.K[1]=128; a.nlog[1]=7; a.off[1]=OWk;
    a.w[2]=Wv;  a.K[2]=128; a.nlog[2]=7; a.off[2]=OWv;
    a.w[3]=Wo;  a.K[3]=128; a.nlog[3]=7; a.off[3]=OWo;
    a.w[4]=Wg1; a.K[4]=128; a.nlog[4]=8; a.off[4]=OWg1;
    a.w[5]=Wg2; a.K[5]=256; a.nlog[5]=7; a.off[5]=OWg2;
    a.w[6]=Wm1; a.K[6]=128; a.nlog[6]=8; a.off[6]=OWm1;
    a.w[7]=Wm2; a.K[7]=256; a.nlog[7]=7; a.off[7]=OWm2;
    wprep_k<<<dim3(128, 8), blk, 0, stream>>>(a, wfr);
  }
  // QKV projections
  {
    MJob jq{x, nullptr, wfr+OWq, wfr+OWq+16384, bq_v, nullptr, q};
    MJob jk{x, nullptr, wfr+OWk, wfr+OWk+16384, bk_v, nullptr, kbuf};
    MJob jv{x, nullptr, wfr+OWv, wfr+OWv+16384, bv_v, nullptr, vbuf};
    gemm_mfma_k<0,0,0,128,0><<<dim3(1,128,3), blk512, 0, stream>>>(jq, jk, jv, 128, psum, psq, 0);
  }
  // Fused attention + entropy + edge masks + bucket placement (XCD-swizzled)
  attn_edge_k<<<dim3(8448), blk, 0, stream>>>(q, kbuf, vbuf, temp, fcp, ffp,
                                              ei, out + 3408384, cursor, meta, out);
  // Fused GINE gather + Wo projection (+ BN colsums t=0,1), XCD-swizzled
  {
    MJob j0{fcp, nullptr, wfr+OWo, wfr+OWo+16384, bo_v, nullptr, acr};
    MJob j1{ffp, nullptr, wfr+OWo, wfr+OWo+16384, bo_v, nullptr, afr};
    gather_wo_k<<<dim3(8448), blk512, 0, stream>>>(x, ea, cursor, meta, agc, agf,
                                                   j0, j1, psum, psq);
  }
  // Fused GINE layer1+layer2 (+ BN colsums t=2,3)
  gine12_k<<<dim3(1,128,2), blk512, 0, stream>>>(x, agc, agf, wfr, bg1v, bg2v,
                                                 mcr, mfr, psum, psq);
  // BN round 1 scale/shift
  bnss_k<<<dim3(4), blk, 0, stream>>>(psum, psq,
      g_attn, g_attn, g_mpnn, g_mpnn, be_attn, be_attn, be_mpnn, be_mpnn, ssr1);
  // Fold BN into Wam weights + bias (merged)
  wamwb_k<<<dim3(130), blk, 0, stream>>>(Wam, bamv, ssr1, wfr, biasC, biasF);
  // Fused fuse-linear + MLP1 + MLP2 (+ BN colsums t=0,1)
  fusemlp_k<<<dim3(1,128,2), blk512, 0, stream>>>(acr, mcr, afr, mfr, wfr,
                                                  biasC, biasF, bm1v, bm2v,
                                                  fmc, fmf, psum, psq);
  // BN round 2 scale/shift
  bnss_k<<<dim3(2), blk, 0, stream>>>(psum, psq,
      g_mlp, g_mlp, g_mlp, g_mlp, be_mlp, be_mlp, be_mlp, be_mlp, sst2);
  // Final features + new_x + encoding pass-through
  final2_k<<<dim3(1152), blk, 0, stream>>>(fmc, fmf, sst2, cenc, fenc, out);
}

// Round 14
// 177.080 us; speedup vs baseline: 1.1272x; 1.0118x over previous
//
#include <hip/hip_runtime.h>

#define TTOK   8192
#define BGR    32
#define NNODE  256
#define DIM    128
#define NH     8
#define HD     16
#define NEDGE  262144
#define SCALE_QK 0.25f
#define BUCKET 96

#define OWq   0
#define OWk   32768
#define OWv   65536
#define OWo   98304
#define OWg1  131072
#define OWg2  196608
#define OWm1  262144
#define OWm2  327680
#define OWamC 393216
#define OWamF 458752

typedef short bf16x8 __attribute__((ext_vector_type(8)));
typedef float f32x4  __attribute__((ext_vector_type(4)));

__device__ __forceinline__ ushort bf_hi(float x, float &rem) {
  unsigned u = __float_as_uint(x) & 0xffff0000u;
  rem = x - __uint_as_float(u);
  return (ushort)(u >> 16);
}
__device__ __forceinline__ ushort bf_rne(float x) {
  unsigned u = __float_as_uint(x);
  u += 0x7fffu + ((u >> 16) & 1u);
  return (ushort)(u >> 16);
}
__device__ __forceinline__ void cvt8(const float* av, bf16x8& ah, bf16x8& al) {
  #pragma unroll
  for (int i = 0; i < 8; i++) {
    float r;
    ah[i] = (short)bf_hi(av[i], r);
    al[i] = (short)bf_rne(r);
  }
}
__device__ __forceinline__ void mfma3(f32x4& acc, const bf16x8& ah, const bf16x8& al,
                                      const bf16x8& bh, const bf16x8& bl) {
  acc = __builtin_amdgcn_mfma_f32_16x16x32_bf16(ah, bh, acc, 0, 0, 0);
  acc = __builtin_amdgcn_mfma_f32_16x16x32_bf16(al, bh, acc, 0, 0, 0);
  acc = __builtin_amdgcn_mfma_f32_16x16x32_bf16(ah, bl, acc, 0, 0, 0);
}

// ---------------- Weight prep (+ cursor zeroing in extra y-slice) ----------------
struct WArg { const float* w[8]; int K[8]; int nlog[8]; int off[8]; };

__global__ __launch_bounds__(256) void wprep_k(WArg a, ushort* out, int* __restrict__ cursor) {
  if (blockIdx.y == 8) {
    if (blockIdx.x < 32) cursor[blockIdx.x * 256 + threadIdx.x] = 0;
    return;
  }
  const int m = blockIdx.y;
  const int K = a.K[m];
  const int nl = a.nlog[m];
  const int sz = K << nl;
  const int e = blockIdx.x * 256 + threadIdx.x;
  if (e >= sz) return;
  const int k = e >> nl, n = e & ((1 << nl) - 1);
  const float x = a.w[m][e];
  float r;
  const ushort h = bf_hi(x, r);
  const ushort l = bf_rne(r);
  const int idx = (((n >> 4) * (K >> 3) + (k >> 3)) << 7) + ((n & 15) << 3) + (k & 7);
  out[a.off[m] + idx] = h;
  out[a.off[m] + sz + idx] = l;
}

// ---------------- MFMA GEMM body (512 thr, 8 waves 2x4, wave-tile 32x32) ----------------
struct MJob {
  const float*  A1;
  const float*  A2;
  const ushort* Wh;
  const ushort* Wl;
  const float*  bias;
  const float*  res;
  float*        C;
};

template<int AMODE, int RELU, int HASRES, int K, int BNSUM>
__device__ __forceinline__ void gemm_body(const MJob jb, int by, int bx, int N,
                                          float* __restrict__ psum,
                                          float* __restrict__ psq, int t)
{
  __shared__ float sredS[128];
  __shared__ float sredQ[128];
  const int tid = threadIdx.x;
  const int w = tid >> 6, lane = tid & 63;
  const int wr = w >> 2, wc = w & 3;
  const int lr = lane & 15, lk = lane >> 4;
  const int bm = by * 64;
  const int bn = bx * 128;
  const int row0 = bm + wr * 32 + lr;
  constexpr int K8 = K / 8;
  f32x4 acc[2][2] = {};

  #pragma unroll
  for (int ks = 0; ks < K / 32; ks++) {
    bf16x8 ah[2], al[2];
    #pragma unroll
    for (int rt = 0; rt < 2; rt++) {
      const int row = row0 + rt * 16;
      float av[8];
      if (AMODE == 0) {
        const float* p = jb.A1 + (size_t)row * K + ks * 32 + lk * 8;
        const f32x4 u0 = *(const f32x4*)p;
        const f32x4 u1 = *(const f32x4*)(p + 4);
        av[0]=u0[0]; av[1]=u0[1]; av[2]=u0[2]; av[3]=u0[3];
        av[4]=u1[0]; av[5]=u1[1]; av[6]=u1[2]; av[7]=u1[3];
      } else if (AMODE == 1) {
        const float* p = jb.A1 + (size_t)row * 128 + ks * 32 + lk * 8;
        const float* q = jb.A2 + (size_t)row * 128 + ks * 32 + lk * 8;
        const f32x4 u0 = *(const f32x4*)p;
        const f32x4 u1 = *(const f32x4*)(p + 4);
        const f32x4 v0 = *(const f32x4*)q;
        const f32x4 v1 = *(const f32x4*)(q + 4);
        av[0]=u0[0]+v0[0]; av[1]=u0[1]+v0[1]; av[2]=u0[2]+v0[2]; av[3]=u0[3]+v0[3];
        av[4]=u1[0]+v1[0]; av[5]=u1[1]+v1[1]; av[6]=u1[2]+v1[2]; av[7]=u1[3]+v1[3];
      } else {
        const float* p = (ks * 32 < 128)
          ? jb.A1 + (size_t)row * 128 + ks * 32 + lk * 8
          : jb.A2 + (size_t)row * 128 + (ks * 32 - 128) + lk * 8;
        const f32x4 u0 = *(const f32x4*)p;
        const f32x4 u1 = *(const f32x4*)(p + 4);
        av[0]=u0[0]; av[1]=u0[1]; av[2]=u0[2]; av[3]=u0[3];
        av[4]=u1[0]; av[5]=u1[1]; av[6]=u1[2]; av[7]=u1[3];
      }
      cvt8(av, ah[rt], al[rt]);
    }
    #pragma unroll
    for (int ct = 0; ct < 2; ct++) {
      const int ntile = (bn >> 4) + wc * 2 + ct;
      const size_t foff = (((size_t)ntile * K8 + ks * 4 + lk) << 7) + ((size_t)lr << 3);
      const bf16x8 bh = *(const bf16x8*)(jb.Wh + foff);
      const bf16x8 bl = *(const bf16x8*)(jb.Wl + foff);
      mfma3(acc[0][ct], ah[0], al[0], bh, bl);
      mfma3(acc[1][ct], ah[1], al[1], bh, bl);
    }
  }

  float csv[2], cqv[2];
  #pragma unroll
  for (int ct = 0; ct < 2; ct++) {
    const int lcol = wc * 32 + ct * 16 + lr;
    const int col = bn + lcol;
    const float bb = jb.bias[col];
    float cs = 0.f, cq = 0.f;
    #pragma unroll
    for (int rt = 0; rt < 2; rt++) {
      #pragma unroll
      for (int r = 0; r < 4; r++) {
        const int row = bm + wr * 32 + rt * 16 + lk * 4 + r;
        float o = acc[rt][ct][r] + bb;
        if (RELU) o = fmaxf(o, 0.f);
        if (HASRES) o += jb.res[(size_t)row * N + col];
        jb.C[(size_t)row * N + col] = o;
        cs += o; cq = fmaf(o, o, cq);
      }
    }
    if (BNSUM) {
      cs += __shfl_xor(cs, 16); cq += __shfl_xor(cq, 16);
      cs += __shfl_xor(cs, 32); cq += __shfl_xor(cq, 32);
      csv[ct] = cs; cqv[ct] = cq;
      if (wr == 1 && lk == 0) { sredS[lcol] = cs; sredQ[lcol] = cq; }
    }
  }
  if (BNSUM) {
    __syncthreads();
    if (wr == 0 && lk == 0) {
      #pragma unroll
      for (int ct = 0; ct < 2; ct++) {
        const int lcol = wc * 32 + ct * 16 + lr;
        psum[((t << 7) + by) * 128 + lcol] = csv[ct] + sredS[lcol];
        psq [((t << 7) + by) * 128 + lcol] = cqv[ct] + sredQ[lcol];
      }
    }
  }
}

template<int AMODE, int RELU, int HASRES, int K, int BNSUM>
__global__ __launch_bounds__(512) void gemm_mfma_k(MJob j0, MJob j1, MJob j2, int N,
                                                   float* __restrict__ psum,
                                                   float* __restrict__ psq, int tix0)
{
  const MJob jb = (blockIdx.z == 0) ? j0 : ((blockIdx.z == 1) ? j1 : j2);
  gemm_body<AMODE,RELU,HASRES,K,BNSUM>(jb, blockIdx.y, blockIdx.x, N, psum, psq, tix0 + blockIdx.z);
}

// ---------------- Fused GINE layer1+layer2 ----------------
__global__ __launch_bounds__(512) void gine12_k(
    const float* __restrict__ x, const float* __restrict__ agc, const float* __restrict__ agf,
    const ushort* __restrict__ wfr,
    const float* __restrict__ bg1v, const float* __restrict__ bg2v,
    float* __restrict__ mcr, float* __restrict__ mfr,
    float* __restrict__ psum, float* __restrict__ psq)
{
  __shared__ float hs[64][260];
  __shared__ float sredS[128];
  __shared__ float sredQ[128];
  const int z = blockIdx.z;
  const float* A2 = z ? agf : agc;
  float* C = z ? mfr : mcr;
  const int tid = threadIdx.x;
  const int w = tid >> 6, lane = tid & 63;
  const int wr = w >> 2, wc = w & 3;
  const int lr = lane & 15, lk = lane >> 4;
  const int bm = blockIdx.y * 64;

  {
    f32x4 acc[2][4] = {};
    const ushort* Wh = wfr + OWg1;
    const ushort* Wl = Wh + 32768;
    #pragma unroll
    for (int ks = 0; ks < 4; ks++) {
      bf16x8 ah[2], al[2];
      #pragma unroll
      for (int rt = 0; rt < 2; rt++) {
        const int row = bm + wr * 32 + rt * 16 + lr;
        const float* p = x  + (size_t)row * 128 + ks * 32 + lk * 8;
        const float* q = A2 + (size_t)row * 128 + ks * 32 + lk * 8;
        const f32x4 u0 = *(const f32x4*)p;
        const f32x4 u1 = *(const f32x4*)(p + 4);
        const f32x4 v0 = *(const f32x4*)q;
        const f32x4 v1 = *(const f32x4*)(q + 4);
        float av[8] = {u0[0]+v0[0], u0[1]+v0[1], u0[2]+v0[2], u0[3]+v0[3],
                       u1[0]+v1[0], u1[1]+v1[1], u1[2]+v1[2], u1[3]+v1[3]};
        cvt8(av, ah[rt], al[rt]);
      }
      #pragma unroll
      for (int ct = 0; ct < 4; ct++) {
        const int ntile = wc * 4 + ct;
        const size_t foff = (((size_t)ntile * 16 + ks * 4 + lk) << 7) + ((size_t)lr << 3);
        const bf16x8 bh = *(const bf16x8*)(Wh + foff);
        const bf16x8 bl = *(const bf16x8*)(Wl + foff);
        mfma3(acc[0][ct], ah[0], al[0], bh, bl);
        mfma3(acc[1][ct], ah[1], al[1], bh, bl);
      }
    }
    #pragma unroll
    for (int ct = 0; ct < 4; ct++) {
      const int col = wc * 64 + ct * 16 + lr;
      const float bb = bg1v[col];
      #pragma unroll
      for (int rt = 0; rt < 2; rt++) {
        #pragma unroll
        for (int r = 0; r < 4; r++) {
          const int lrow = wr * 32 + rt * 16 + lk * 4 + r;
          hs[lrow][col] = fmaxf(acc[rt][ct][r] + bb, 0.f);
        }
      }
    }
  }
  __syncthreads();
  {
    f32x4 acc[2][2] = {};
    const ushort* Wh = wfr + OWg2;
    const ushort* Wl = Wh + 32768;
    #pragma unroll
    for (int ks = 0; ks < 8; ks++) {
      bf16x8 ah[2], al[2];
      #pragma unroll
      for (int rt = 0; rt < 2; rt++) {
        const int lrow = wr * 32 + rt * 16 + lr;
        const float* p = &hs[lrow][ks * 32 + lk * 8];
        const f32x4 u0 = *(const f32x4*)p;
        const f32x4 u1 = *(const f32x4*)(p + 4);
        float av[8] = {u0[0],u0[1],u0[2],u0[3],u1[0],u1[1],u1[2],u1[3]};
        cvt8(av, ah[rt], al[rt]);
      }
      #pragma unroll
      for (int ct = 0; ct < 2; ct++) {
        const int ntile = wc * 2 + ct;
        const size_t foff = (((size_t)ntile * 32 + ks * 4 + lk) << 7) + ((size_t)lr << 3);
        const bf16x8 bh = *(const bf16x8*)(Wh + foff);
        const bf16x8 bl = *(const bf16x8*)(Wl + foff);
        mfma3(acc[0][ct], ah[0], al[0], bh, bl);
        mfma3(acc[1][ct], ah[1], al[1], bh, bl);
      }
    }
    const int t = 2 + z;
    float csv[2], cqv[2];
    #pragma unroll
    for (int ct = 0; ct < 2; ct++) {
      const int lcol = wc * 32 + ct * 16 + lr;
      const float bb = bg2v[lcol];
      float cs = 0.f, cq = 0.f;
      #pragma unroll
      for (int rt = 0; rt < 2; rt++) {
        #pragma unroll
        for (int r = 0; r < 4; r++) {
          const int row = bm + wr * 32 + rt * 16 + lk * 4 + r;
          const float o = acc[rt][ct][r] + bb;
          C[(size_t)row * 128 + lcol] = o;
          cs += o; cq = fmaf(o, o, cq);
        }
      }
      cs += __shfl_xor(cs, 16); cq += __shfl_xor(cq, 16);
      cs += __shfl_xor(cs, 32); cq += __shfl_xor(cq, 32);
      csv[ct] = cs; cqv[ct] = cq;
      if (wr == 1 && lk == 0) { sredS[lcol] = cs; sredQ[lcol] = cq; }
    }
    __syncthreads();
    if (wr == 0 && lk == 0) {
      #pragma unroll
      for (int ct = 0; ct < 2; ct++) {
        const int lcol = wc * 32 + ct * 16 + lr;
        psum[((t << 7) + blockIdx.y) * 128 + lcol] = csv[ct] + sredS[lcol];
        psq [((t << 7) + blockIdx.y) * 128 + lcol] = cqv[ct] + sredQ[lcol];
      }
    }
  }
}

// ---------------- Fused fuse-linear + MLP1 + MLP2 ----------------
__global__ __launch_bounds__(512) void fusemlp_k(
    const float* __restrict__ acr, const float* __restrict__ mcr,
    const float* __restrict__ afr, const float* __restrict__ mfr,
    const ushort* __restrict__ wfr,
    const float* __restrict__ biasC, const float* __restrict__ biasF,
    const float* __restrict__ bm1v, const float* __restrict__ bm2v,
    float* __restrict__ fmc, float* __restrict__ fmf,
    float* __restrict__ psum, float* __restrict__ psq)
{
  __shared__ float ft[64][132];
  __shared__ float hs[64][260];
  __shared__ float sredS[128];
  __shared__ float sredQ[128];
  const int z = blockIdx.z;
  const float* A1 = z ? afr : acr;
  const float* A2 = z ? mfr : mcr;
  const float* bA = z ? biasF : biasC;
  float* C = z ? fmf : fmc;
  const ushort* WamH = wfr + (z ? OWamF : OWamC);
  const int tid = threadIdx.x;
  const int w = tid >> 6, lane = tid & 63;
  const int wr = w >> 2, wc = w & 3;
  const int lr = lane & 15, lk = lane >> 4;
  const int bm = blockIdx.y * 64;

  {
    f32x4 acc[2][2] = {};
    const ushort* Wl = WamH + 32768;
    #pragma unroll
    for (int ks = 0; ks < 8; ks++) {
      bf16x8 ah[2], al[2];
      #pragma unroll
      for (int rt = 0; rt < 2; rt++) {
        const int row = bm + wr * 32 + rt * 16 + lr;
        const float* p = (ks < 4)
          ? A1 + (size_t)row * 128 + ks * 32 + lk * 8
          : A2 + (size_t)row * 128 + (ks - 4) * 32 + lk * 8;
        const f32x4 u0 = *(const f32x4*)p;
        const f32x4 u1 = *(const f32x4*)(p + 4);
        float av[8] = {u0[0],u0[1],u0[2],u0[3],u1[0],u1[1],u1[2],u1[3]};
        cvt8(av, ah[rt], al[rt]);
      }
      #pragma unroll
      for (int ct = 0; ct < 2; ct++) {
        const int ntile = wc * 2 + ct;
        const size_t foff = (((size_t)ntile * 32 + ks * 4 + lk) << 7) + ((size_t)lr << 3);
        const bf16x8 bh = *(const bf16x8*)(WamH + foff);
        const bf16x8 bl = *(const bf16x8*)(Wl + foff);
        mfma3(acc[0][ct], ah[0], al[0], bh, bl);
        mfma3(acc[1][ct], ah[1], al[1], bh, bl);
      }
    }
    #pragma unroll
    for (int ct = 0; ct < 2; ct++) {
      const int col = wc * 32 + ct * 16 + lr;
      const float bb = bA[col];
      #pragma unroll
      for (int rt = 0; rt < 2; rt++) {
        #pragma unroll
        for (int r = 0; r < 4; r++) {
          const int lrow = wr * 32 + rt * 16 + lk * 4 + r;
          ft[lrow][col] = acc[rt][ct][r] + bb;
        }
      }
    }
  }
  __syncthreads();
  {
    f32x4 acc[2][4] = {};
    const ushort* Wh = wfr + OWm1;
    const ushort* Wl = Wh + 32768;
    #pragma unroll
    for (int ks = 0; ks < 4; ks++) {
      bf16x8 ah[2], al[2];
      #pragma unroll
      for (int rt = 0; rt < 2; rt++) {
        const int lrow = wr * 32 + rt * 16 + lr;
        const float* p = &ft[lrow][ks * 32 + lk * 8];
        const f32x4 u0 = *(const f32x4*)p;
        const f32x4 u1 = *(const f32x4*)(p + 4);
        float av[8] = {u0[0],u0[1],u0[2],u0[3],u1[0],u1[1],u1[2],u1[3]};
        cvt8(av, ah[rt], al[rt]);
      }
      #pragma unroll
      for (int ct = 0; ct < 4; ct++) {
        const int ntile = wc * 4 + ct;
        const size_t foff = (((size_t)ntile * 16 + ks * 4 + lk) << 7) + ((size_t)lr << 3);
        const bf16x8 bh = *(const bf16x8*)(Wh + foff);
        const bf16x8 bl = *(const bf16x8*)(Wl + foff);
        mfma3(acc[0][ct], ah[0], al[0], bh, bl);
        mfma3(acc[1][ct], ah[1], al[1], bh, bl);
      }
    }
    #pragma unroll
    for (int ct = 0; ct < 4; ct++) {
      const int col = wc * 64 + ct * 16 + lr;
      const float bb = bm1v[col];
      #pragma unroll
      for (int rt = 0; rt < 2; rt++) {
        #pragma unroll
        for (int r = 0; r < 4; r++) {
          const int lrow = wr * 32 + rt * 16 + lk * 4 + r;
          hs[lrow][col] = fmaxf(acc[rt][ct][r] + bb, 0.f);
        }
      }
    }
  }
  __syncthreads();
  {
    f32x4 acc[2][2] = {};
    const ushort* Wh = wfr + OWm2;
    const ushort* Wl = Wh + 32768;
    #pragma unroll
    for (int ks = 0; ks < 8; ks++) {
      bf16x8 ah[2], al[2];
      #pragma unroll
      for (int rt = 0; rt < 2; rt++) {
        const int lrow = wr * 32 + rt * 16 + lr;
        const float* p = &hs[lrow][ks * 32 + lk * 8];
        const f32x4 u0 = *(const f32x4*)p;
        const f32x4 u1 = *(const f32x4*)(p + 4);
        float av[8] = {u0[0],u0[1],u0[2],u0[3],u1[0],u1[1],u1[2],u1[3]};
        cvt8(av, ah[rt], al[rt]);
      }
      #pragma unroll
      for (int ct = 0; ct < 2; ct++) {
        const int ntile = wc * 2 + ct;
        const size_t foff = (((size_t)ntile * 32 + ks * 4 + lk) << 7) + ((size_t)lr << 3);
        const bf16x8 bh = *(const bf16x8*)(Wh + foff);
        const bf16x8 bl = *(const bf16x8*)(Wl + foff);
        mfma3(acc[0][ct], ah[0], al[0], bh, bl);
        mfma3(acc[1][ct], ah[1], al[1], bh, bl);
      }
    }
    float csv[2], cqv[2];
    #pragma unroll
    for (int ct = 0; ct < 2; ct++) {
      const int lcol = wc * 32 + ct * 16 + lr;
      const float bb = bm2v[lcol];
      float cs = 0.f, cq = 0.f;
      #pragma unroll
      for (int rt = 0; rt < 2; rt++) {
        #pragma unroll
        for (int r = 0; r < 4; r++) {
          const int lrow = wr * 32 + rt * 16 + lk * 4 + r;
          const float o = acc[rt][ct][r] + bb + ft[lrow][lcol];
          C[(size_t)(bm + lrow) * 128 + lcol] = o;
          cs += o; cq = fmaf(o, o, cq);
        }
      }
      cs += __shfl_xor(cs, 16); cq += __shfl_xor(cq, 16);
      cs += __shfl_xor(cs, 32); cq += __shfl_xor(cq, 32);
      csv[ct] = cs; cqv[ct] = cq;
      if (wr == 1 && lk == 0) { sredS[lcol] = cs; sredQ[lcol] = cq; }
    }
    __syncthreads();
    if (wr == 0 && lk == 0) {
      #pragma unroll
      for (int ct = 0; ct < 2; ct++) {
        const int lcol = wc * 32 + ct * 16 + lr;
        psum[((z << 7) + blockIdx.y) * 128 + lcol] = csv[ct] + sredS[lcol];
        psq [((z << 7) + blockIdx.y) * 128 + lcol] = cqv[ct] + sredQ[lcol];
      }
    }
  }
}

// ---------------- Fused gather + Wo GEMM (XCD-swizzled, fixed buckets, meta prefetch) ----------------
__global__ __launch_bounds__(512) void gather_wo_k(
    const float* __restrict__ x, const float* __restrict__ ea,
    const int* __restrict__ cnt, const int4* __restrict__ meta,
    float* __restrict__ aggrC, float* __restrict__ aggrF,
    MJob j0, MJob j1, float* __restrict__ psum, float* __restrict__ psq)
{
  const int xcd = blockIdx.x & 7;
  const int j = blockIdx.x >> 3;
  if (j < 32) {
    const int wid = xcd + 8 * j;
    gemm_body<0,0,0,128,1>((wid < 128) ? j0 : j1, wid & 127, 0, 128, psum, psq, wid >> 7);
    return;
  }
  const int jj = j - 32;
  const int g = xcd + 8 * (jj >> 8);
  const int n = g * 256 + (jj & 255);
  __shared__ float sC[16][128];
  __shared__ float sF[16][128];
  const int tid = threadIdx.x;
  const int s = tid >> 5;
  const int c4 = (tid & 31) * 4;
  const int base = n * BUCKET;
  const int end = base + cnt[n];
  float4 aC = make_float4(0,0,0,0), aF = make_float4(0,0,0,0);
  int i = base + s;
  if (i < end) {
    int4 md = meta[i];
    for (;;) {
      const int inext = i + 16;
      int4 mdn;
      if (inext < end) mdn = meta[inext];
      const float4 u = *(const float4*)(x  + (size_t)md.x * DIM + c4);
      const float4 w = *(const float4*)(ea + (size_t)md.y * DIM + c4);
      const float mc = __int_as_float(md.z);
      const float mf = 1.f - mc;
      const float g0 = fmaxf(u.x + w.x, 0.f);
      const float g1 = fmaxf(u.y + w.y, 0.f);
      const float g2 = fmaxf(u.z + w.z, 0.f);
      const float g3 = fmaxf(u.w + w.w, 0.f);
      aC.x = fmaf(g0, mc, aC.x); aC.y = fmaf(g1, mc, aC.y);
      aC.z = fmaf(g2, mc, aC.z); aC.w = fmaf(g3, mc, aC.w);
      aF.x = fmaf(g0, mf, aF.x); aF.y = fmaf(g1, mf, aF.y);
      aF.z = fmaf(g2, mf, aF.z); aF.w = fmaf(g3, mf, aF.w);
      if (inext >= end) break;
      md = mdn; i = inext;
    }
  }
  *(float4*)&sC[s][c4] = aC;
  *(float4*)&sF[s][c4] = aF;
  __syncthreads();
  if (tid < 128) {
    float t = 0.f;
    #pragma unroll
    for (int kk = 0; kk < 16; kk++) t += sC[kk][tid];
    aggrC[(size_t)n * DIM + tid] = t;
  } else if (tid < 256) {
    const int col = tid - 128;
    float t = 0.f;
    #pragma unroll
    for (int kk = 0; kk < 16; kk++) t += sF[kk][col];
    aggrF[(size_t)n * DIM + col] = t;
  }
}

// ---------------- Fused attention + edge mask/bucket placement (XCD-swizzled) ----------------
__global__ __launch_bounds__(256) void attn_edge_k(
    const float* __restrict__ q, const float* __restrict__ k, const float* __restrict__ v,
    const float* __restrict__ tptr, float* __restrict__ fc, float* __restrict__ ff,
    const int* __restrict__ ei, float* __restrict__ maskout,
    int* __restrict__ cursor, int4* __restrict__ meta,
    float* __restrict__ dout)
{
  __shared__ float Ks[256][20];
  __shared__ float Vs[256][20];
  __shared__ float red[4][2];
  __shared__ float kmax_s[4];
  const int tid = threadIdx.x;
  const int xcd = blockIdx.x & 7;
  const int j = blockIdx.x >> 3;

  if (j >= 32) {
    const int jj = j - 32;
    const int g = xcd + 8 * (jj >> 8);
    const int s = jj & 255;
    const int e = g * 8192 + s * 32 + (tid >> 3);
    const int h = tid & 7;
    const int src = ei[e];
    const int dst = ei[NEDGE + e];
    const float* qr = q + (size_t)src * DIM + h*HD;
    const float* kr = k + (size_t)dst * DIM + h*HD;
    float sdot = 0.f;
    #pragma unroll
    for (int p = 0; p < 4; p++) {
      float4 a = *(const float4*)(qr + 4*p);
      float4 c = *(const float4*)(kr + 4*p);
      sdot += a.x*c.x + a.y*c.y + a.z*c.z + a.w*c.w;
    }
    sdot *= SCALE_QK;
    const float sig = 1.f / (1.f + __expf(-sdot));
    maskout[e * 8 + h] = sig;
    float m = sig;
    m += __shfl_xor(m, 1); m += __shfl_xor(m, 2); m += __shfl_xor(m, 4);
    if ((tid & 7) == 0) {
      const int pos = atomicAdd(&cursor[dst], 1);
      meta[dst * BUCKET + pos] = make_int4(src, e, __float_as_int(m * 0.125f), 0);
    }
    return;
  }

  const int b = (j >> 3) * 8 + xcd;
  const int h = j & 7;
  const int bh = b * 8 + h;
  float k2 = 0.f;
  {
    const float* kr = k + ((size_t)(b*NNODE + tid))*DIM + h*HD;
    const float* vr = v + ((size_t)(b*NNODE + tid))*DIM + h*HD;
    #pragma unroll
    for (int p = 0; p < 4; p++) {
      float4 kv = *(const float4*)(kr + 4*p);
      *(float4*)&Ks[tid][4*p] = kv;
      k2 += kv.x*kv.x + kv.y*kv.y + kv.z*kv.z + kv.w*kv.w;
      *(float4*)&Vs[tid][4*p] = *(const float4*)(vr + 4*p);
    }
  }
  #pragma unroll
  for (int off = 1; off < 64; off <<= 1) k2 = fmaxf(k2, __shfl_xor(k2, off));
  if ((tid & 63) == 0) kmax_s[tid >> 6] = k2;
  const int pr  = tid >> 1;
  const int par = tid & 1;
  const int r0 = pr * 2;
  const float sc = SCALE_QK / tptr[0];
  float qa[16], qb[16];
  float q2a = 0.f, q2b = 0.f;
  {
    const float* qr = q + ((size_t)(b*NNODE + r0))*DIM + h*HD;
    #pragma unroll
    for (int p = 0; p < 4; p++) {
      float4 a = *(const float4*)(qr + 4*p);
      qa[4*p+0]=a.x*sc; qa[4*p+1]=a.y*sc; qa[4*p+2]=a.z*sc; qa[4*p+3]=a.w*sc;
      q2a += qa[4*p]*qa[4*p] + qa[4*p+1]*qa[4*p+1] + qa[4*p+2]*qa[4*p+2] + qa[4*p+3]*qa[4*p+3];
      float4 c = *(const float4*)(qr + DIM + 4*p);
      qb[4*p+0]=c.x*sc; qb[4*p+1]=c.y*sc; qb[4*p+2]=c.z*sc; qb[4*p+3]=c.w*sc;
      q2b += qb[4*p]*qb[4*p] + qb[4*p+1]*qb[4*p+1] + qb[4*p+2]*qb[4*p+2] + qb[4*p+3]*qb[4*p+3];
    }
  }
  __syncthreads();
  const float kmax2 = fmaxf(fmaxf(kmax_s[0], kmax_s[1]), fmaxf(kmax_s[2], kmax_s[3]));
  const float Ma = sqrtf(q2a * kmax2), Mb = sqrtf(q2b * kmax2);
  const float mna = -Ma, mnb = -Mb;

  float zca=0,zfa=0,Eca=0,Efa=0, zcb=0,zfb=0,Ecb=0,Efb=0;
  float oca[16], ofa[16], ocb[16], ofb[16];
  #pragma unroll
  for (int d = 0; d < 16; d++) { oca[d]=0.f; ofa[d]=0.f; ocb[d]=0.f; ofb[d]=0.f; }
  for (int jn = par; jn < NNODE; jn += 2) {
    const float4 k0 = *(const float4*)&Ks[jn][0];
    const float4 k1 = *(const float4*)&Ks[jn][4];
    const float4 k2v = *(const float4*)&Ks[jn][8];
    const float4 k3 = *(const float4*)&Ks[jn][12];
    float sa = qa[0]*k0.x; float sb = qb[0]*k0.x;
    sa = fmaf(qa[1],k0.y,sa); sb = fmaf(qb[1],k0.y,sb);
    sa = fmaf(qa[2],k0.z,sa); sb = fmaf(qb[2],k0.z,sb);
    sa = fmaf(qa[3],k0.w,sa); sb = fmaf(qb[3],k0.w,sb);
    sa = fmaf(qa[4],k1.x,sa); sb = fmaf(qb[4],k1.x,sb);
    sa = fmaf(qa[5],k1.y,sa); sb = fmaf(qb[5],k1.y,sb);
    sa = fmaf(qa[6],k1.z,sa); sb = fmaf(qb[6],k1.z,sb);
    sa = fmaf(qa[7],k1.w,sa); sb = fmaf(qb[7],k1.w,sb);
    sa = fmaf(qa[8],k2v.x,sa); sb = fmaf(qb[8],k2v.x,sb);
    sa = fmaf(qa[9],k2v.y,sa); sb = fmaf(qb[9],k2v.y,sb);
    sa = fmaf(qa[10],k2v.z,sa); sb = fmaf(qb[10],k2v.z,sb);
    sa = fmaf(qa[11],k2v.w,sa); sb = fmaf(qb[11],k2v.w,sb);
    sa = fmaf(qa[12],k3.x,sa); sb = fmaf(qb[12],k3.x,sb);
    sa = fmaf(qa[13],k3.y,sa); sb = fmaf(qb[13],k3.y,sb);
    sa = fmaf(qa[14],k3.z,sa); sb = fmaf(qb[14],k3.z,sb);
    sa = fmaf(qa[15],k3.w,sa); sb = fmaf(qb[15],k3.w,sb);
    const float eca = __expf(sa - Ma);
    const float efa = __expf(mna - sa);
    const float ecb = __expf(sb - Mb);
    const float efb = __expf(mnb - sb);
    zca += eca; zfa += efa; zcb += ecb; zfb += efb;
    Eca = fmaf(eca, sa, Eca); Efa = fmaf(efa, -sa, Efa);
    Ecb = fmaf(ecb, sb, Ecb); Efb = fmaf(efb, -sb, Efb);
    const float4 v0 = *(const float4*)&Vs[jn][0];
    const float4 v1 = *(const float4*)&Vs[jn][4];
    const float4 v2 = *(const float4*)&Vs[jn][8];
    const float4 v3 = *(const float4*)&Vs[jn][12];
    const float vv[16] = {v0.x,v0.y,v0.z,v0.w, v1.x,v1.y,v1.z,v1.w,
                          v2.x,v2.y,v2.z,v2.w, v3.x,v3.y,v3.z,v3.w};
    #pragma unroll
    for (int d = 0; d < 16; d++) {
      oca[d] = fmaf(eca, vv[d], oca[d]);
      ofa[d] = fmaf(efa, vv[d], ofa[d]);
      ocb[d] = fmaf(ecb, vv[d], ocb[d]);
      ofb[d] = fmaf(efb, vv[d], ofb[d]);
    }
  }
  zca += __shfl_xor(zca, 1); zfa += __shfl_xor(zfa, 1);
  zcb += __shfl_xor(zcb, 1); zfb += __shfl_xor(zfb, 1);
  Eca += __shfl_xor(Eca, 1); Efa += __shfl_xor(Efa, 1);
  Ecb += __shfl_xor(Ecb, 1); Efb += __shfl_xor(Efb, 1);
  #pragma unroll
  for (int d = 0; d < 16; d++) {
    oca[d] += __shfl_xor(oca[d], 1);
    ofa[d] += __shfl_xor(ofa[d], 1);
    ocb[d] += __shfl_xor(ocb[d], 1);
    ofb[d] += __shfl_xor(ofb[d], 1);
  }
  float entc = 0.f, entf = 0.f;
  if (par == 0) {
    const float rca = 1.f/zca, rfa = 1.f/zfa, rcb = 1.f/zcb, rfb = 1.f/zfb;
    entc = (Ma + __logf(zca) - Eca*rca) + (Mb + __logf(zcb) - Ecb*rcb);
    entf = (-mna + __logf(zfa) - Efa*rfa) + (-mnb + __logf(zfb) - Efb*rfb);
    float* pc = fc + ((size_t)(b*NNODE + r0))*DIM + h*HD;
    float* pf = ff + ((size_t)(b*NNODE + r0))*DIM + h*HD;
    #pragma unroll
    for (int p = 0; p < 4; p++) {
      *(float4*)(pc + 4*p)       = make_float4(oca[4*p]*rca, oca[4*p+1]*rca, oca[4*p+2]*rca, oca[4*p+3]*rca);
      *(float4*)(pc + DIM + 4*p) = make_float4(ocb[4*p]*rcb, ocb[4*p+1]*rcb, ocb[4*p+2]*rcb, ocb[4*p+3]*rcb);
      *(float4*)(pf + 4*p)       = make_float4(ofa[4*p]*rfa, ofa[4*p+1]*rfa, ofa[4*p+2]*rfa, ofa[4*p+3]*rfa);
      *(float4*)(pf + DIM + 4*p) = make_float4(ofb[4*p]*rfb, ofb[4*p+1]*rfb, ofb[4*p+2]*rfb, ofb[4*p+3]*rfb);
    }
  }
  #pragma unroll
  for (int off = 1; off < 64; off <<= 1) {
    entc += __shfl_xor(entc, off);
    entf += __shfl_xor(entf, off);
  }
  const int wv = tid >> 6;
  if ((tid & 63) == 0) { red[wv][0] = entc; red[wv][1] = entf; }
  __syncthreads();
  if (tid == 0) {
    const float tc = red[0][0]+red[1][0]+red[2][0]+red[3][0];
    const float tf = red[0][1]+red[1][1]+red[2][1]+red[3][1];
    dout[3145728 + bh] = tc * (1.0f/256.0f);
    dout[3145984 + bh] = tf * (1.0f/256.0f);
  }
}

// ---------------- Wam weights + bias, BN round-1 computed in-block ----------------
__global__ __launch_bounds__(256) void wamwb2_k(
    const float* __restrict__ Wam, const float* __restrict__ bam,
    const float* __restrict__ psum, const float* __restrict__ psq,
    const float* __restrict__ gA, const float* __restrict__ bA,
    const float* __restrict__ gM, const float* __restrict__ bM,
    ushort* __restrict__ outbase,
    float* __restrict__ biasC, float* __restrict__ biasF)
{
  __shared__ float2 ssl[4][128];
  const int bx = blockIdx.x;
  const int tid = threadIdx.x;
  {
    const int col = tid & 127;
    for (int ti = tid >> 7; ti < 4; ti += 2) {
      float s = 0.f, sq = 0.f;
      #pragma unroll 8
      for (int c = 0; c < 128; c++) {
        s  += psum[((ti << 7) + c) * 128 + col];
        sq += psq [((ti << 7) + c) * 128 + col];
      }
      const float mean = s * (1.f/8192.f);
      const float var  = sq * (1.f/8192.f) - mean*mean;
      const float istd = rsqrtf(var + 1e-5f);
      const float g = (ti < 2) ? gA[col] : gM[col];
      const float bb = (ti < 2) ? bA[col] : bM[col];
      const float sc = g * istd;
      ssl[ti][col] = make_float2(sc, bb - mean*sc);
    }
  }
  __syncthreads();
  if (bx < 128) {
    const int e = bx * 256 + tid;
    const int k = e >> 7, n = e & 127;
    const float wv = Wam[e];
    const int idx = (((n >> 4) * 32 + (k >> 3)) << 7) + ((n & 15) << 3) + (k & 7);
    #pragma unroll
    for (int br = 0; br < 2; br++) {
      const float2 st = (k < 128) ? ssl[br][k] : ssl[2 + br][k - 128];
      const float wp = st.x * wv;
      float r;
      const ushort h = bf_hi(wp, r);
      const ushort l = bf_rne(r);
      ushort* oh = outbase + 393216 + br * 65536;
      oh[idx] = h; oh[32768 + idx] = l;
    }
    return;
  }
  __shared__ float lred[128];
  const int br = bx - 128;
  const int n = tid & 127, half = tid >> 7;
  const float2* st = half ? ssl[2 + br] : ssl[br];
  float a0=0.f, a1=0.f, a2=0.f, a3=0.f;
  #pragma unroll 8
  for (int kk = 0; kk < 128; kk += 4) {
    const int kb = half*128 + kk;
    a0 = fmaf(st[kk+0].y, Wam[(kb+0)*128 + n], a0);
    a1 = fmaf(st[kk+1].y, Wam[(kb+1)*128 + n], a1);
    a2 = fmaf(st[kk+2].y, Wam[(kb+2)*128 + n], a2);
    a3 = fmaf(st[kk+3].y, Wam[(kb+3)*128 + n], a3);
  }
  const float tot = (a0 + a1) + (a2 + a3);
  if (half) lred[n] = tot;
  __syncthreads();
  if (!half) {
    float* bout = br ? biasF : biasC;
    bout[n] = bam[n] + tot + lred[n];
  }
}

// ---------------- BN round-2 scale/shift ----------------
__global__ __launch_bounds__(256) void bnss_k(
    const float* __restrict__ psum, const float* __restrict__ psq,
    const float* g0, const float* g1,
    const float* b0, const float* b1,
    float2* __restrict__ out)
{
  __shared__ float ls[128], lq[128];
  const int ti = blockIdx.x;
  const int tid = threadIdx.x;
  const int col = tid & 127, half = tid >> 7;
  const float* g = (ti == 0) ? g0 : g1;
  const float* bb = (ti == 0) ? b0 : b1;
  float s = 0.f, sq = 0.f;
  const int cbase = half * 64;
  #pragma unroll 8
  for (int c = 0; c < 64; c++) {
    s  += psum[(ti*128 + cbase + c)*128 + col];
    sq += psq [(ti*128 + cbase + c)*128 + col];
  }
  if (half) { ls[col] = s; lq[col] = sq; }
  __syncthreads();
  if (!half) {
    s += ls[col]; sq += lq[col];
    const float mean = s * (1.f/8192.f);
    const float var  = sq * (1.f/8192.f) - mean*mean;
    const float istd = rsqrtf(var + 1e-5f);
    const float sc = g[col] * istd;
    out[ti*128 + col] = make_float2(sc, bb[col] - mean*sc);
  }
}

// ---------------- Final outputs + encoding pass-through ----------------
__global__ __launch_bounds__(256) void final2_k(
    const float* __restrict__ fmc, const float* __restrict__ fmf,
    const float2* __restrict__ sst2,
    const float* __restrict__ cenc, const float* __restrict__ fenc,
    float* __restrict__ dout)
{
  const int bx = blockIdx.x;
  const int tid = threadIdx.x;
  if (bx >= 1024) {
    const int i = (bx - 1024) * 256 + tid;
    const float4 c = ((const float4*)cenc)[i];
    const float4 f = ((const float4*)fenc)[i];
    ((float4*)(dout + 3146240))[i] = c;
    ((float4*)(dout + 3277312))[i] = f;
    return;
  }
  const int idx4 = bx * 256 + tid;
  const int base = idx4 * 4;
  const int col = base & 127;
  const float4 a = *(const float4*)(fmc + base);
  const float4 b = *(const float4*)(fmf + base);
  const float2 s0 = sst2[col],     s1 = sst2[col+1],     s2 = sst2[col+2],     s3 = sst2[col+3];
  const float2 t0 = sst2[128+col], t1 = sst2[128+col+1], t2 = sst2[128+col+2], t3 = sst2[128+col+3];
  const float c0 = a.x*s0.x + s0.y, c1 = a.y*s1.x + s1.y, c2 = a.z*s2.x + s2.y, c3 = a.w*s3.x + s3.y;
  const float f0 = b.x*t0.x + t0.y, f1 = b.y*t1.x + t1.y, f2 = b.z*t2.x + t2.y, f3 = b.w*t3.x + t3.y;
  *(float4*)(dout + 1048576 + base) = make_float4(c0,c1,c2,c3);
  *(float4*)(dout + 2097152 + base) = make_float4(f0,f1,f2,f3);
  *(float4*)(dout + base) = make_float4(0.5f*(c0+f0), 0.5f*(c1+f1), 0.5f*(c2+f2), 0.5f*(c3+f3));
}

// ---------------- Launcher ----------------
extern "C" void kernel_launch(void* const* d_in, const int* in_sizes, int n_in,
                              void* d_out, int out_size, void* d_ws, size_t ws_size,
                              hipStream_t stream)
{
  const float* x    = (const float*)d_in[0];
  const int*   ei   = (const int*)  d_in[2];
  const float* ea   = (const float*)d_in[3];
  const float* temp = (const float*)d_in[4];
  const float* cenc = (const float*)d_in[5];
  const float* fenc = (const float*)d_in[6];
  const float* Wq   = (const float*)d_in[7];
  const float* bq_v = (const float*)d_in[8];
  const float* Wk   = (const float*)d_in[9];
  const float* bk_v = (const float*)d_in[10];
  const float* Wv   = (const float*)d_in[11];
  const float* bv_v = (const float*)d_in[12];
  const float* Wo   = (const float*)d_in[13];
  const float* bo_v = (const float*)d_in[14];
  const float* Wg1  = (const float*)d_in[15];
  const float* bg1v = (const float*)d_in[16];
  const float* Wg2  = (const float*)d_in[17];
  const float* bg2v = (const float*)d_in[18];
  const float* Wam  = (const float*)d_in[19];
  const float* bamv = (const float*)d_in[20];
  const float* Wm1  = (const float*)d_in[21];
  const float* bm1v = (const float*)d_in[22];
  const float* Wm2  = (const float*)d_in[23];
  const float* bm2v = (const float*)d_in[24];
  const float* g_attn  = (const float*)d_in[25];
  const float* be_attn = (const float*)d_in[26];
  const float* g_mpnn  = (const float*)d_in[27];
  const float* be_mpnn = (const float*)d_in[28];
  const float* g_mlp   = (const float*)d_in[29];
  const float* be_mlp  = (const float*)d_in[30];

  float* out = (float*)d_out;
  float* ws  = (float*)d_ws;
  const size_t M1 = 1048576;

  float* q    = ws + 0*M1;
  float* kbuf = ws + 1*M1;
  float* vbuf = ws + 2*M1;
  float* fcp  = ws + 3*M1;
  float* ffp  = ws + 4*M1;
  float* acr  = ws + 5*M1;
  float* afr  = ws + 6*M1;
  float* agc  = ws + 7*M1;
  float* agf  = ws + 8*M1;
  float* psum = ws + 13*M1;            // 65536
  float* psq  = psum + 65536;          // 65536
  float* biasC = psq + 65536;          // 128
  float* biasF = biasC + 128;          // 128
  float2* sst2 = (float2*)(biasF + 128); // 256 float2
  ushort* wfr = (ushort*)(ws + 14*M1); // 1MB
  int4* meta  = (int4*)(ws + 16*M1);   // 12.6MB
  int* cursor = (int*)(ws + 9*M1);     // 8192 (doubles as per-node count)
  // reuses (sequenced by stream order)
  float* mcr = q;
  float* mfr = kbuf;
  float* fmc = ffp;
  float* fmf = agc;

  const dim3 blk(256);
  const dim3 blk512(512);

  // Weight prep + cursor zeroing
  {
    WArg a;
    a.w[0]=Wq;  a.K[0]=128; a.nlog[0]=7; a.off[0]=OWq;
    a.w[1]=Wk;  a.K[1]=128; a.nlog[1]=7; a.off[1]=OWk;
    a.w[2]=Wv;  a.K[2]=128; a.nlog[2]=7; a.off[2]=OWv;
    a.w[3]=Wo;  a.K[3]=128; a.nlog[3]=7; a.off[3]=OWo;
    a.w[4]=Wg1; a.K[4]=128; a.nlog[4]=8; a.off[4]=OWg1;
    a.w[5]=Wg2; a.K[5]=256; a.nlog[5]=7; a.off[5]=OWg2;
    a.w[6]=Wm1; a.K[6]=128; a.nlog[6]=8; a.off[6]=OWm1;
    a.w[7]=Wm2; a.K[7]=256; a.nlog[7]=7; a.off[7]=OWm2;
    wprep_k<<<dim3(128, 9), blk, 0, stream>>>(a, wfr, cursor);
  }
  // QKV projections
  {
    MJob jq{x, nullptr, wfr+OWq, wfr+OWq+16384, bq_v, nullptr, q};
    MJob jk{x, nullptr, wfr+OWk, wfr+OWk+16384, bk_v, nullptr, kbuf};
    MJob jv{x, nullptr, wfr+OWv, wfr+OWv+16384, bv_v, nullptr, vbuf};
    gemm_mfma_k<0,0,0,128,0><<<dim3(1,128,3), blk512, 0, stream>>>(jq, jk, jv, 128, psum, psq, 0);
  }
  // Fused attention + entropy + edge masks + bucket placement (XCD-swizzled)
  attn_edge_k<<<dim3(8448), blk, 0, stream>>>(q, kbuf, vbuf, temp, fcp, ffp,
                                              ei, out + 3408384, cursor, meta, out);
  // Fused GINE gather + Wo projection (+ BN colsums t=0,1), XCD-swizzled
  {
    MJob j0{fcp, nullptr, wfr+OWo, wfr+OWo+16384, bo_v, nullptr, acr};
    MJob j1{ffp, nullptr, wfr+OWo, wfr+OWo+16384, bo_v, nullptr, afr};
    gather_wo_k<<<dim3(8448), blk512, 0, stream>>>(x, ea, cursor, meta, agc, agf,
                                                   j0, j1, psum, psq);
  }
  // Fused GINE layer1+layer2 (+ BN colsums t=2,3)
  gine12_k<<<dim3(1,128,2), blk512, 0, stream>>>(x, agc, agf, wfr, bg1v, bg2v,
                                                 mcr, mfr, psum, psq);
  // Fold BN round 1 into Wam weights + bias (BN computed in-block)
  wamwb2_k<<<dim3(130), blk, 0, stream>>>(Wam, bamv, psum, psq,
      g_attn, be_attn, g_mpnn, be_mpnn, wfr, biasC, biasF);
  // Fused fuse-linear + MLP1 + MLP2 (+ BN colsums t=0,1)
  fusemlp_k<<<dim3(1,128,2), blk512, 0, stream>>>(acr, mcr, afr, mfr, wfr,
                                                  biasC, biasF, bm1v, bm2v,
                                                  fmc, fmf, psum, psq);
  // BN round 2 scale/shift
  bnss_k<<<dim3(2), blk, 0, stream>>>(psum, psq, g_mlp, g_mlp, be_mlp, be_mlp, sst2);
  // Final features + new_x + encoding pass-through
  final2_k<<<dim3(1152), blk, 0, stream>>>(fmc, fmf, sst2, cenc, fenc, out);
}